// Round 10
// baseline (1245.634 us; speedup 1.0000x reference)
//
#include <hip/hip_runtime.h>
#include <hip/hip_fp16.h>
#include <math.h>
#include <stdint.h>

#define NEG 0.2f
#define CSHIFT 8
#define MAXNB 512          // supports n <= 131072 (17-bit src pack)
#define CHUNK 2048

// ============================ node transform (fp16 h1 out) ============================

__global__ __launch_bounds__(256) void k1_node(const float* __restrict__ x,
    const float* __restrict__ W1, const float* __restrict__ a1s, const float* __restrict__ a1d,
    __half* __restrict__ h1, float* __restrict__ as1, float* __restrict__ ad1, int n)
{
    __shared__ float wt[8 * 128];
    __shared__ float av[16];
    for (int i = threadIdx.x; i < 1024; i += 256) {
        int r = i >> 3, k = i & 7;
        wt[k * 128 + r] = W1[i];
    }
    if (threadIdx.x < 8)        av[threadIdx.x] = a1s[threadIdx.x];
    else if (threadIdx.x < 16)  av[threadIdx.x] = a1d[threadIdx.x - 8];
    __syncthreads();

    int lane = threadIdx.x & 31;
    int node = blockIdx.x * 8 + (threadIdx.x >> 5);
    if (node >= n) return;

    float4 xv = ((const float4*)(x + (size_t)node * 128))[lane];
    float p[8];
#pragma unroll
    for (int k = 0; k < 8; ++k) {
        float4 wv = ((const float4*)(wt + k * 128))[lane];
        p[k] = xv.x * wv.x + xv.y * wv.y + xv.z * wv.z + xv.w * wv.w;
    }
#pragma unroll
    for (int off = 16; off; off >>= 1)
#pragma unroll
        for (int k = 0; k < 8; ++k) p[k] += __shfl_down(p[k], off, 32);

    if (lane == 0) {
        float s = 0.f, d = 0.f;
        union { float4 f; __half2 h[4]; } u;
#pragma unroll
        for (int k = 0; k < 8; ++k) {
            s += p[k] * av[k];
            d += p[k] * av[8 + k];
        }
#pragma unroll
        for (int q = 0; q < 4; ++q) u.h[q] = __floats2half2_rn(p[2 * q], p[2 * q + 1]);
        ((float4*)h1)[node] = u.f;   // 16B fp16 row
        as1[node] = s;
        ad1[node] = d;
    }
}

// ============================ bucket-sort build (coarse only) ============================

__global__ __launch_bounds__(256) void p1a(const int* __restrict__ dst, int* __restrict__ gmat,
                                           int E, int NB)
{
    __shared__ int h[MAXNB];
    for (int i = threadIdx.x; i < NB; i += 256) h[i] = 0;
    __syncthreads();
    int base = blockIdx.x * CHUNK;
    int end = base + CHUNK; if (end > E) end = E;
    for (int i = base + threadIdx.x; i < end; i += 256)
        atomicAdd(&h[dst[i] >> CSHIFT], 1);
    __syncthreads();
    int* row = gmat + (size_t)blockIdx.x * NB;
    for (int i = threadIdx.x; i < NB; i += 256) row[i] = h[i];
}

__global__ __launch_bounds__(256) void pcol(const int* __restrict__ gmat, int* __restrict__ pbaseRel,
    int* __restrict__ total, int NBLK, int NB)
{
    __shared__ int wsum[4];
    int b = blockIdx.x;
    int tid = threadIdx.x;
    int chunk = (NBLK + 255) >> 8;
    int k0 = tid * chunk;
    int s = 0;
    for (int j = 0; j < chunk; ++j) {
        int k = k0 + j;
        if (k < NBLK) s += gmat[(size_t)k * NB + b];
    }
    int lane = tid & 63, w = tid >> 6;
    int sc = s;
#pragma unroll
    for (int off = 1; off < 64; off <<= 1) {
        int t = __shfl_up(sc, off, 64);
        if (lane >= off) sc += t;
    }
    if (lane == 63) wsum[w] = sc;
    __syncthreads();
    if (tid == 0) { int a = 0; for (int i = 0; i < 4; ++i) { int t = wsum[i]; wsum[i] = a; a += t; } }
    __syncthreads();
    int run = sc - s + wsum[w];
    for (int j = 0; j < chunk; ++j) {
        int k = k0 + j;
        if (k < NBLK) {
            int gv = gmat[(size_t)k * NB + b];
            pbaseRel[(size_t)k * NB + b] = run;
            run += gv;
        }
    }
    if (tid == 255) total[b] = run;
}

__global__ __launch_bounds__(512) void ptot(const int* __restrict__ total, int* __restrict__ cptr,
                                            int NB, int E)
{
    __shared__ int wsum[8];
    int b = threadIdx.x;
    int v = b < NB ? total[b] : 0;
    int lane = b & 63, w = b >> 6;
    int s = v;
#pragma unroll
    for (int off = 1; off < 64; off <<= 1) {
        int t = __shfl_up(s, off, 64);
        if (lane >= off) s += t;
    }
    if (lane == 63) wsum[w] = s;
    __syncthreads();
    if (b == 0) { int a = 0; for (int i = 0; i < 8; ++i) { int t = wsum[i]; wsum[i] = a; a += t; } }
    __syncthreads();
    int excl = s - v + wsum[w];
    if (b < NB) cptr[b] = excl;
    if (b == 0) cptr[NB] = E;
}

__global__ __launch_bounds__(256) void p1bM(const int* __restrict__ src, const int* __restrict__ dst,
    const int* __restrict__ cptr, const int* __restrict__ pbaseRel, unsigned* __restrict__ stage,
    int E, int NB)
{
    __shared__ int bbase[MAXNB], ccur[MAXNB];
    const int* prow = pbaseRel + (size_t)blockIdx.x * NB;
    for (int i = threadIdx.x; i < NB; i += 256) { bbase[i] = cptr[i] + prow[i]; ccur[i] = 0; }
    __syncthreads();
    int base = blockIdx.x * CHUNK;
    int end = base + CHUNK; if (end > E) end = E;
    for (int i = base + threadIdx.x; i < end; i += 256) {
        int d = dst[i];
        int b = d >> CSHIFT;
        int off = atomicAdd(&ccur[b], 1);
        stage[bbase[b] + off] = ((unsigned)(d & ((1 << CSHIFT) - 1)) << 17) | (unsigned)src[i];
    }
}

// ============================ bucket-local aggregation ============================

// Layer 1: LDS-accumulate per bucket, then fused normalize+ReLU+@W2+alpha2 epilogue.
__global__ __launch_bounds__(1024) void kb1(const unsigned* __restrict__ stage,
    const int* __restrict__ cptr, const float* __restrict__ as1, const float* __restrict__ ad1,
    const __half* __restrict__ h1, const float* __restrict__ b1, const float* __restrict__ W2,
    const float* __restrict__ a2s, const float* __restrict__ a2d,
    __half* __restrict__ g, float* __restrict__ as2, float* __restrict__ ad2, int n)
{
    __shared__ float acc[256][9];   // 8 feat + wsum; stride 9 coprime w/ 32 banks
    __shared__ float adl[256];
    __shared__ float w2s[128], a2sv[16], a2dv[16], b1v[8];
    int tid = threadIdx.x;
    int b = blockIdx.x;
    int nbase = b << CSHIFT;

    if (tid < 128) w2s[tid] = W2[tid];
    else if (tid < 144) a2sv[tid - 128] = a2s[tid - 128];
    else if (tid < 160) a2dv[tid - 144] = a2d[tid - 144];
    else if (tid < 168) b1v[tid - 160] = b1[tid - 160];
    for (int i = tid; i < 256 * 9; i += 1024) ((float*)acc)[i] = 0.f;
    if (tid >= 512 && tid < 768) {
        int nd = nbase + tid - 512;
        adl[tid - 512] = nd < n ? ad1[nd] : 0.f;
    }
    __syncthreads();

    int s0 = cptr[b], s1 = cptr[b + 1];
    for (int i = s0 + tid; i < s1; i += 1024) {
        unsigned pk = stage[i];
        int f = pk >> 17;
        int s = (int)(pk & 0x1FFFFu);
        float t = as1[s] + adl[f];
        float w = __expf(t > 0.f ? t : NEG * t);  // softmax shift skipped: exact ratio
        union { float4 fv; __half2 h[4]; } u;
        u.fv = ((const float4*)h1)[s];
        atomicAdd(&acc[f][8], w);
#pragma unroll
        for (int q = 0; q < 4; ++q) {
            float2 hv = __half22float2(u.h[q]);
            atomicAdd(&acc[f][2 * q + 0], w * hv.x);
            atomicAdd(&acc[f][2 * q + 1], w * hv.y);
        }
    }
    __syncthreads();

    if (tid < 256) {
        int node = nbase + tid;
        if (node < n) {
            float wsum = acc[tid][8];
            float inv = wsum > 0.f ? 1.f / wsum : 0.f;
            float h[8];
#pragma unroll
            for (int k = 0; k < 8; ++k) {
                float v = acc[tid][k] * inv + b1v[k];
                h[k] = v > 0.f ? v : 0.f;
            }
            float ps = 0.f, pd = 0.f;
            union { float4 fv[2]; __half2 h[8]; } go;
#pragma unroll
            for (int c = 0; c < 16; c += 2) {
                float g0 = 0.f, g1 = 0.f;
#pragma unroll
                for (int k = 0; k < 8; ++k) {
                    g0 += h[k] * w2s[k * 16 + c];
                    g1 += h[k] * w2s[k * 16 + c + 1];
                }
                ps += g0 * a2sv[c] + g1 * a2sv[c + 1];
                pd += g0 * a2dv[c] + g1 * a2dv[c + 1];
                go.h[c >> 1] = __floats2half2_rn(g0, g1);
            }
            ((float4*)g)[(size_t)node * 2 + 0] = go.fv[0];
            ((float4*)g)[(size_t)node * 2 + 1] = go.fv[1];
            as2[node] = ps;
            ad2[node] = pd;
        }
    }
}

// Layer 2: LDS-accumulate per bucket, fused log_softmax epilogue -> out.
__global__ __launch_bounds__(1024) void kb2(const unsigned* __restrict__ stage,
    const int* __restrict__ cptr, const float* __restrict__ as2, const float* __restrict__ ad2,
    const __half* __restrict__ g, const float* __restrict__ b2, float* __restrict__ out, int n)
{
    __shared__ float acc[256][17];  // 16 classes + wsum; stride 17 coprime w/ 32 banks
    __shared__ float adl[256];
    __shared__ float b2v[16];
    int tid = threadIdx.x;
    int b = blockIdx.x;
    int nbase = b << CSHIFT;

    if (tid < 16) b2v[tid] = b2[tid];
    for (int i = tid; i < 256 * 17; i += 1024) ((float*)acc)[i] = 0.f;
    if (tid >= 512 && tid < 768) {
        int nd = nbase + tid - 512;
        adl[tid - 512] = nd < n ? ad2[nd] : 0.f;
    }
    __syncthreads();

    int s0 = cptr[b], s1 = cptr[b + 1];
    for (int i = s0 + tid; i < s1; i += 1024) {
        unsigned pk = stage[i];
        int f = pk >> 17;
        int s = (int)(pk & 0x1FFFFu);
        float t = as2[s] + adl[f];
        float w = __expf(t > 0.f ? t : NEG * t);
        union { float4 fv[2]; __half2 h[8]; } u;
        u.fv[0] = ((const float4*)g)[(size_t)s * 2 + 0];
        u.fv[1] = ((const float4*)g)[(size_t)s * 2 + 1];
        atomicAdd(&acc[f][16], w);
#pragma unroll
        for (int q = 0; q < 8; ++q) {
            float2 gv = __half22float2(u.h[q]);
            atomicAdd(&acc[f][2 * q + 0], w * gv.x);
            atomicAdd(&acc[f][2 * q + 1], w * gv.y);
        }
    }
    __syncthreads();

    if (tid < 256) {
        int node = nbase + tid;
        if (node < n) {
            float wsum = acc[tid][16];
            float inv = wsum > 0.f ? 1.f / wsum : 0.f;
            float o[16], m = -1e30f;
#pragma unroll
            for (int c = 0; c < 16; ++c) {
                o[c] = acc[tid][c] * inv + b2v[c];
                m = fmaxf(m, o[c]);
            }
            float se = 0.f;
#pragma unroll
            for (int c = 0; c < 16; ++c) se += __expf(o[c] - m);
            float l = m + __logf(se);
            float4 ov;
            float* op = out + (size_t)node * 16;
#pragma unroll
            for (int q = 0; q < 4; ++q) {
                ov.x = o[4 * q + 0] - l; ov.y = o[4 * q + 1] - l;
                ov.z = o[4 * q + 2] - l; ov.w = o[4 * q + 3] - l;
                ((float4*)op)[q] = ov;
            }
        }
    }
}

// ============================ fallback: pure atomic path (fp32) ============================

__global__ __launch_bounds__(256) void k1_nodeF(const float* __restrict__ x,
    const float* __restrict__ W1, const float* __restrict__ a1s, const float* __restrict__ a1d,
    float* __restrict__ h1, float* __restrict__ as1, float* __restrict__ ad1, int n)
{
    __shared__ float wt[8 * 128];
    __shared__ float av[16];
    for (int i = threadIdx.x; i < 1024; i += 256) {
        int r = i >> 3, k = i & 7;
        wt[k * 128 + r] = W1[i];
    }
    if (threadIdx.x < 8)        av[threadIdx.x] = a1s[threadIdx.x];
    else if (threadIdx.x < 16)  av[threadIdx.x] = a1d[threadIdx.x - 8];
    __syncthreads();

    int lane = threadIdx.x & 31;
    int node = blockIdx.x * 8 + (threadIdx.x >> 5);
    if (node >= n) return;

    float4 xv = ((const float4*)(x + (size_t)node * 128))[lane];
    float p[8];
#pragma unroll
    for (int k = 0; k < 8; ++k) {
        float4 wv = ((const float4*)(wt + k * 128))[lane];
        p[k] = xv.x * wv.x + xv.y * wv.y + xv.z * wv.z + xv.w * wv.w;
    }
#pragma unroll
    for (int off = 16; off; off >>= 1)
#pragma unroll
        for (int k = 0; k < 8; ++k) p[k] += __shfl_down(p[k], off, 32);

    if (lane == 0) {
        float s = 0.f, d = 0.f;
#pragma unroll
        for (int k = 0; k < 8; ++k) {
            h1[(size_t)node * 8 + k] = p[k];
            s += p[k] * av[k];
            d += p[k] * av[8 + k];
        }
        as1[node] = s;
        ad1[node] = d;
    }
}

template <int F>
__global__ __launch_bounds__(256) void k_edge(const int* __restrict__ src, const int* __restrict__ dst,
    const float* __restrict__ as, const float* __restrict__ ad, const float* __restrict__ feat,
    float* __restrict__ denom, float* __restrict__ acc, int E)
{
    int e = blockIdx.x * 256 + threadIdx.x;
    if (e >= E) return;
    int s = src[e], d = dst[e];
    float t = as[s] + ad[d];
    float w = __expf(t > 0.f ? t : NEG * t);
    atomicAdd(denom + d, w);
    const float* fs = feat + (size_t)s * F;
    float* ac = acc + (size_t)d * F;
#pragma unroll
    for (int k = 0; k < F; ++k) atomicAdd(ac + k, w * fs[k]);
}

__global__ __launch_bounds__(256) void k3_node(const float* __restrict__ denom1,
    const float* __restrict__ acc1, const float* __restrict__ b1,
    const float* __restrict__ W2, const float* __restrict__ a2s, const float* __restrict__ a2d,
    float* __restrict__ g, float* __restrict__ as2, float* __restrict__ ad2, int n)
{
    __shared__ float w2[128];
    __shared__ float aa[32];
    __shared__ float bb[8];
    if (threadIdx.x < 128) w2[threadIdx.x] = W2[threadIdx.x];
    if (threadIdx.x >= 128 && threadIdx.x < 144) aa[threadIdx.x - 128] = a2s[threadIdx.x - 128];
    if (threadIdx.x >= 144 && threadIdx.x < 160) aa[16 + threadIdx.x - 144] = a2d[threadIdx.x - 144];
    if (threadIdx.x >= 160 && threadIdx.x < 168) bb[threadIdx.x - 160] = b1[threadIdx.x - 160];
    __syncthreads();

    int node = blockIdx.x * 256 + threadIdx.x;
    if (node >= n) return;
    float dn = denom1[node];
    float inv = dn > 0.f ? 1.f / dn : 0.f;
    float h[8];
#pragma unroll
    for (int k = 0; k < 8; ++k) {
        float v = acc1[(size_t)node * 8 + k] * inv + bb[k];
        h[k] = v > 0.f ? v : 0.f;
    }
    float s = 0.f, dd = 0.f;
#pragma unroll
    for (int c = 0; c < 16; ++c) {
        float gv = 0.f;
#pragma unroll
        for (int k = 0; k < 8; ++k) gv += h[k] * w2[k * 16 + c];
        g[(size_t)node * 16 + c] = gv;
        s += gv * aa[c];
        dd += gv * aa[16 + c];
    }
    as2[node] = s;
    ad2[node] = dd;
}

__global__ __launch_bounds__(256) void k5_final(const float* __restrict__ denom2,
    const float* __restrict__ acc2, const float* __restrict__ b2, float* __restrict__ out, int n)
{
    __shared__ float bb[16];
    if (threadIdx.x < 16) bb[threadIdx.x] = b2[threadIdx.x];
    __syncthreads();

    int node = blockIdx.x * 256 + threadIdx.x;
    if (node >= n) return;
    float dn = denom2[node];
    float inv = dn > 0.f ? 1.f / dn : 0.f;
    float o[16];
    float m = -1e30f;
#pragma unroll
    for (int c = 0; c < 16; ++c) {
        o[c] = acc2[(size_t)node * 16 + c] * inv + bb[c];
        m = fmaxf(m, o[c]);
    }
    float se = 0.f;
#pragma unroll
    for (int c = 0; c < 16; ++c) {
        o[c] -= m;
        se += __expf(o[c]);
    }
    float l = __logf(se);
#pragma unroll
    for (int c = 0; c < 16; ++c) out[(size_t)node * 16 + c] = o[c] - l;
}

// ============================ launch ============================

static inline char* align256(char* p) {
    return (char*)(((uintptr_t)p + 255) & ~(uintptr_t)255);
}

extern "C" void kernel_launch(void* const* d_in, const int* in_sizes, int n_in,
                              void* d_out, int out_size, void* d_ws, size_t ws_size,
                              hipStream_t stream)
{
    const float* x    = (const float*)d_in[0];
    const int*   eidx = (const int*)d_in[1];
    const float* W1   = (const float*)d_in[2];
    const float* a1s  = (const float*)d_in[3];
    const float* a1d  = (const float*)d_in[4];
    const float* b1   = (const float*)d_in[5];
    const float* W2   = (const float*)d_in[6];
    const float* a2s  = (const float*)d_in[7];
    const float* a2d  = (const float*)d_in[8];
    const float* b2   = (const float*)d_in[9];
    float* out = (float*)d_out;

    const int n = in_sizes[0] / 128;
    const int E = in_sizes[1] / 2;
    const int* src = eidx;
    const int* dst = eidx + E;
    const int NB = (n + 255) >> CSHIFT;
    const int NBLK = (E + CHUNK - 1) / CHUNK;

    // ---- tier-0: bucket-sort + bucket-local LDS aggregation ----
    {
        char* p = (char*)d_ws;
        char* p0 = p;
        unsigned* stage = (unsigned*)p;   p = align256(p + (size_t)E * 4);
        int* gmat     = (int*)p;          p = align256(p + (size_t)NBLK * NB * 4);
        int* pbaseRel = (int*)p;          p = align256(p + (size_t)NBLK * NB * 4);
        int* total    = (int*)p;          p = align256(p + (size_t)NB * 4);
        int* cptr     = (int*)p;          p = align256(p + (size_t)(NB + 1) * 4);
        __half* h1    = (__half*)p;       p = align256(p + (size_t)8 * n * 2);
        __half* g     = (__half*)p;       p = align256(p + (size_t)16 * n * 2);
        float* as1    = (float*)p;        p = align256(p + (size_t)n * 4);
        float* ad1    = (float*)p;        p = align256(p + (size_t)n * 4);
        float* as2    = (float*)p;        p = align256(p + (size_t)n * 4);
        float* ad2    = (float*)p;        p = align256(p + (size_t)n * 4);
        size_t needed = (size_t)(p - p0);

        if (n <= 131072 && NB <= MAXNB && ws_size >= needed) {
            k1_node<<<(n + 7) / 8, 256, 0, stream>>>(x, W1, a1s, a1d, h1, as1, ad1, n);

            p1a<<<NBLK, 256, 0, stream>>>(dst, gmat, E, NB);
            pcol<<<NB, 256, 0, stream>>>(gmat, pbaseRel, total, NBLK, NB);
            ptot<<<1, 512, 0, stream>>>(total, cptr, NB, E);
            p1bM<<<NBLK, 256, 0, stream>>>(src, dst, cptr, pbaseRel, stage, E, NB);

            kb1<<<NB, 1024, 0, stream>>>(stage, cptr, as1, ad1, h1, b1, W2, a2s, a2d,
                                         g, as2, ad2, n);
            kb2<<<NB, 1024, 0, stream>>>(stage, cptr, as2, ad2, g, b2, out, n);
            return;
        }
    }

    // ---- fallback: pure atomic path (fp32) ----
    {
        float* ws     = (float*)d_ws;
        float* denom1 = ws;
        float* acc1   = ws + (size_t)n;
        float* denom2 = ws + (size_t)9 * n;
        float* acc2   = ws + (size_t)10 * n;
        float* h1     = ws + (size_t)26 * n;
        float* as1    = ws + (size_t)34 * n;
        float* ad1    = ws + (size_t)35 * n;
        float* g      = ws + (size_t)36 * n;
        float* as2    = ws + (size_t)52 * n;
        float* ad2    = ws + (size_t)53 * n;

        hipMemsetAsync(ws, 0, (size_t)26 * n * sizeof(float), stream);
        k1_nodeF<<<(n + 7) / 8, 256, 0, stream>>>(x, W1, a1s, a1d, h1, as1, ad1, n);
        k_edge<8><<<(E + 255) / 256, 256, 0, stream>>>(src, dst, as1, ad1, h1, denom1, acc1, E);
        k3_node<<<(n + 255) / 256, 256, 0, stream>>>(denom1, acc1, b1, W2, a2s, a2d, g, as2, ad2, n);
        k_edge<16><<<(E + 255) / 256, 256, 0, stream>>>(src, dst, as2, ad2, g, denom2, acc2, E);
        k5_final<<<(n + 255) / 256, 256, 0, stream>>>(denom2, acc2, b2, out, n);
    }
}

// Round 11
// 379.547 us; speedup vs baseline: 3.2819x; 3.2819x over previous
//
#include <hip/hip_runtime.h>
#include <hip/hip_fp16.h>
#include <math.h>
#include <stdint.h>

#define NEG 0.2f
#define CSHIFT 8
#define MAXNB 512          // supports n <= 131072 (17-bit src pack)
#define CHUNK 2048

// ============================ node transform (fp16 h1 out) ============================

__global__ __launch_bounds__(256) void k1_node(const float* __restrict__ x,
    const float* __restrict__ W1, const float* __restrict__ a1s, const float* __restrict__ a1d,
    __half* __restrict__ h1, float* __restrict__ as1, float* __restrict__ ad1, int n)
{
    __shared__ float wt[8 * 128];
    __shared__ float av[16];
    for (int i = threadIdx.x; i < 1024; i += 256) {
        int r = i >> 3, k = i & 7;
        wt[k * 128 + r] = W1[i];
    }
    if (threadIdx.x < 8)        av[threadIdx.x] = a1s[threadIdx.x];
    else if (threadIdx.x < 16)  av[threadIdx.x] = a1d[threadIdx.x - 8];
    __syncthreads();

    int lane = threadIdx.x & 31;
    int node = blockIdx.x * 8 + (threadIdx.x >> 5);
    if (node >= n) return;

    float4 xv = ((const float4*)(x + (size_t)node * 128))[lane];
    float p[8];
#pragma unroll
    for (int k = 0; k < 8; ++k) {
        float4 wv = ((const float4*)(wt + k * 128))[lane];
        p[k] = xv.x * wv.x + xv.y * wv.y + xv.z * wv.z + xv.w * wv.w;
    }
#pragma unroll
    for (int off = 16; off; off >>= 1)
#pragma unroll
        for (int k = 0; k < 8; ++k) p[k] += __shfl_down(p[k], off, 32);

    if (lane == 0) {
        float s = 0.f, d = 0.f;
        union { float4 f; __half2 h[4]; } u;
#pragma unroll
        for (int k = 0; k < 8; ++k) {
            s += p[k] * av[k];
            d += p[k] * av[8 + k];
        }
#pragma unroll
        for (int q = 0; q < 4; ++q) u.h[q] = __floats2half2_rn(p[2 * q], p[2 * q + 1]);
        ((float4*)h1)[node] = u.f;   // 16B fp16 row
        as1[node] = s;
        ad1[node] = d;
    }
}

// ============================ bucket-sort CSR build (all-parallel, atomic-free) ============================

__global__ __launch_bounds__(256) void p1a(const int* __restrict__ dst, int* __restrict__ gmat,
                                           int E, int NB)
{
    __shared__ int h[MAXNB];
    for (int i = threadIdx.x; i < NB; i += 256) h[i] = 0;
    __syncthreads();
    int base = blockIdx.x * CHUNK;
    int end = base + CHUNK; if (end > E) end = E;
    for (int i = base + threadIdx.x; i < end; i += 256)
        atomicAdd(&h[dst[i] >> CSHIFT], 1);
    __syncthreads();
    int* row = gmat + (size_t)blockIdx.x * NB;
    for (int i = threadIdx.x; i < NB; i += 256) row[i] = h[i];
}

__global__ __launch_bounds__(256) void pcol(const int* __restrict__ gmat, int* __restrict__ pbaseRel,
    int* __restrict__ total, int NBLK, int NB)
{
    __shared__ int wsum[4];
    int b = blockIdx.x;
    int tid = threadIdx.x;
    int chunk = (NBLK + 255) >> 8;
    int k0 = tid * chunk;
    int s = 0;
    for (int j = 0; j < chunk; ++j) {
        int k = k0 + j;
        if (k < NBLK) s += gmat[(size_t)k * NB + b];
    }
    int lane = tid & 63, w = tid >> 6;
    int sc = s;
#pragma unroll
    for (int off = 1; off < 64; off <<= 1) {
        int t = __shfl_up(sc, off, 64);
        if (lane >= off) sc += t;
    }
    if (lane == 63) wsum[w] = sc;
    __syncthreads();
    if (tid == 0) { int a = 0; for (int i = 0; i < 4; ++i) { int t = wsum[i]; wsum[i] = a; a += t; } }
    __syncthreads();
    int run = sc - s + wsum[w];
    for (int j = 0; j < chunk; ++j) {
        int k = k0 + j;
        if (k < NBLK) {
            int gv = gmat[(size_t)k * NB + b];
            pbaseRel[(size_t)k * NB + b] = run;
            run += gv;
        }
    }
    if (tid == 255) total[b] = run;
}

__global__ __launch_bounds__(512) void ptot(const int* __restrict__ total, int* __restrict__ cptr,
                                            int* __restrict__ row_ptr, int NB, int n, int E)
{
    __shared__ int wsum[8];
    int b = threadIdx.x;
    int v = b < NB ? total[b] : 0;
    int lane = b & 63, w = b >> 6;
    int s = v;
#pragma unroll
    for (int off = 1; off < 64; off <<= 1) {
        int t = __shfl_up(s, off, 64);
        if (lane >= off) s += t;
    }
    if (lane == 63) wsum[w] = s;
    __syncthreads();
    if (b == 0) { int a = 0; for (int i = 0; i < 8; ++i) { int t = wsum[i]; wsum[i] = a; a += t; } }
    __syncthreads();
    int excl = s - v + wsum[w];
    if (b < NB) cptr[b] = excl;
    if (b == 0) { cptr[NB] = E; row_ptr[n] = E; }
}

__global__ __launch_bounds__(256) void p1bM(const int* __restrict__ src, const int* __restrict__ dst,
    const int* __restrict__ cptr, const int* __restrict__ pbaseRel, unsigned* __restrict__ stage,
    int E, int NB)
{
    __shared__ int bbase[MAXNB], ccur[MAXNB];
    const int* prow = pbaseRel + (size_t)blockIdx.x * NB;
    for (int i = threadIdx.x; i < NB; i += 256) { bbase[i] = cptr[i] + prow[i]; ccur[i] = 0; }
    __syncthreads();
    int base = blockIdx.x * CHUNK;
    int end = base + CHUNK; if (end > E) end = E;
    for (int i = base + threadIdx.x; i < end; i += 256) {
        int d = dst[i];
        int b = d >> CSHIFT;
        int off = atomicAdd(&ccur[b], 1);
        stage[bbase[b] + off] = ((unsigned)(d & ((1 << CSHIFT) - 1)) << 17) | (unsigned)src[i];
    }
}

__global__ __launch_bounds__(512) void p2(const unsigned* __restrict__ stage,
    const int* __restrict__ cptr, int* __restrict__ colsrc, int* __restrict__ row_ptr, int n)
{
    int b = blockIdx.x;
    int nbase = b << CSHIFT;
    int NN = n - nbase; if (NN > 256) NN = 256;
    __shared__ int h[256], bps[256], cc[256];
    __shared__ int wsum[4];
    int tid = threadIdx.x;
    for (int i = tid; i < 256; i += 512) { h[i] = 0; cc[i] = 0; }
    __syncthreads();
    int s0 = cptr[b], s1 = cptr[b + 1];
    for (int i = s0 + tid; i < s1; i += 512)
        atomicAdd(&h[stage[i] >> 17], 1);
    __syncthreads();
    int v = 0, sc = 0;
    int lane = tid & 63, w = tid >> 6;
    if (tid < 256) {
        v = h[tid];
        sc = v;
#pragma unroll
        for (int off = 1; off < 64; off <<= 1) {
            int t = __shfl_up(sc, off, 64);
            if (lane >= off) sc += t;
        }
        if (lane == 63) wsum[w] = sc;
    }
    __syncthreads();
    if (tid == 0) { int a = 0; for (int i = 0; i < 4; ++i) { int t = wsum[i]; wsum[i] = a; a += t; } }
    __syncthreads();
    if (tid < 256) {
        int excl = sc - v + wsum[w];
        bps[tid] = s0 + excl;
        if (tid < NN) row_ptr[nbase + tid] = s0 + excl;
    }
    __syncthreads();
    for (int i = s0 + tid; i < s1; i += 512) {
        unsigned p = stage[i];
        int f = p >> 17;
        int off = atomicAdd(&cc[f], 1);
        colsrc[bps[f] + off] = (int)(p & 0x1FFFFu);
    }
}

// ============================ gathers (fp16 features) ============================

// Layer 1 gather, fused with layer-2 node transform; h1 fp16 in, g fp16 out
__global__ __launch_bounds__(256) void k_gather8f(const int* __restrict__ row_ptr,
    const int* __restrict__ colsrc, const float* __restrict__ as, const float* __restrict__ ad,
    const __half* __restrict__ feat, const float* __restrict__ b1,
    const float* __restrict__ W2, const float* __restrict__ a2s, const float* __restrict__ a2d,
    __half* __restrict__ g, float* __restrict__ as2, float* __restrict__ ad2, int n)
{
    __shared__ float w2s[128], a2sv[16], a2dv[16], b1v[8];
    if (threadIdx.x < 128) w2s[threadIdx.x] = W2[threadIdx.x];
    else if (threadIdx.x < 144) a2sv[threadIdx.x - 128] = a2s[threadIdx.x - 128];
    else if (threadIdx.x < 160) a2dv[threadIdx.x - 144] = a2d[threadIdx.x - 144];
    else if (threadIdx.x < 168) b1v[threadIdx.x - 160] = b1[threadIdx.x - 160];
    __syncthreads();

    int node = (blockIdx.x * 256 + threadIdx.x) >> 6;
    int lane = threadIdx.x & 63;
    if (node >= n) return;
    int start = row_ptr[node], end = row_ptr[node + 1];
    float adn = ad[node];
    float wsum = 0.f;
    float acc[8];
#pragma unroll
    for (int k = 0; k < 8; ++k) acc[k] = 0.f;

    for (int i = start + lane; i < end; i += 64) {
        int s = colsrc[i];
        float t = as[s] + adn;
        float w = __expf(t > 0.f ? t : NEG * t);  // max-shift skipped: |t| small, exact ratio
        wsum += w;
        union { float4 fv; __half2 h[4]; } u;
        u.fv = ((const float4*)feat)[s];          // 16B fp16 row
#pragma unroll
        for (int q = 0; q < 4; ++q) {
            float2 hv = __half22float2(u.h[q]);
            acc[2 * q + 0] += w * hv.x;
            acc[2 * q + 1] += w * hv.y;
        }
    }
#pragma unroll
    for (int off = 32; off; off >>= 1) {
        wsum += __shfl_xor(wsum, off, 64);
#pragma unroll
        for (int k = 0; k < 8; ++k) acc[k] += __shfl_xor(acc[k], off, 64);
    }
    float inv = wsum > 0.f ? 1.f / wsum : 0.f;
    float h[8];
#pragma unroll
    for (int k = 0; k < 8; ++k) {
        float v = acc[k] * inv + b1v[k];
        h[k] = v > 0.f ? v : 0.f;
    }
    if (lane < 16) {
        float gv = 0.f;
#pragma unroll
        for (int k = 0; k < 8; ++k) gv += h[k] * w2s[k * 16 + lane];
        float po = __shfl_xor(gv, 1, 16);          // partner class value
        if ((lane & 1) == 0)
            ((__half2*)(g + (size_t)node * 16))[lane >> 1] = __floats2half2_rn(gv, po);
        float ps = gv * a2sv[lane];
        float pd = gv * a2dv[lane];
#pragma unroll
        for (int off = 8; off; off >>= 1) {
            ps += __shfl_xor(ps, off, 16);
            pd += __shfl_xor(pd, off, 16);
        }
        if (lane == 0) { as2[node] = ps; ad2[node] = pd; }
    }
}

// Layer 2 gather with fused log_softmax; g fp16 in
__global__ __launch_bounds__(256) void k_gather16(const int* __restrict__ row_ptr,
    const int* __restrict__ colsrc, const float* __restrict__ as, const float* __restrict__ ad,
    const __half* __restrict__ feat, const float* __restrict__ bias, float* __restrict__ outp, int n)
{
    int node = (blockIdx.x * 256 + threadIdx.x) >> 6;
    int lane = threadIdx.x & 63;
    if (node >= n) return;
    int start = row_ptr[node], end = row_ptr[node + 1];
    float adn = ad[node];
    float wsum = 0.f;
    float acc[16];
#pragma unroll
    for (int k = 0; k < 16; ++k) acc[k] = 0.f;

    for (int i = start + lane; i < end; i += 64) {
        int s = colsrc[i];
        float t = as[s] + adn;
        float w = __expf(t > 0.f ? t : NEG * t);
        wsum += w;
        union { float4 fv[2]; __half2 h[8]; } u;
        const float4* gs = (const float4*)(feat + (size_t)s * 16);  // 32B fp16 row
        u.fv[0] = gs[0];
        u.fv[1] = gs[1];
#pragma unroll
        for (int q = 0; q < 8; ++q) {
            float2 gv = __half22float2(u.h[q]);
            acc[2 * q + 0] += w * gv.x;
            acc[2 * q + 1] += w * gv.y;
        }
    }
#pragma unroll
    for (int off = 32; off; off >>= 1) {
        wsum += __shfl_xor(wsum, off, 64);
#pragma unroll
        for (int k = 0; k < 16; ++k) acc[k] += __shfl_xor(acc[k], off, 64);
    }
    float inv = wsum > 0.f ? 1.f / wsum : 0.f;
    float o[16], m = -1e30f;
#pragma unroll
    for (int c = 0; c < 16; ++c) {
        o[c] = acc[c] * inv + bias[c];
        m = fmaxf(m, o[c]);
    }
    float se = 0.f;
#pragma unroll
    for (int c = 0; c < 16; ++c) se += __expf(o[c] - m);
    float l = m + __logf(se);
    if (lane < 16) outp[(size_t)node * 16 + lane] = o[lane] - l;
}

// ============================ fallback: pure atomic path (fp32) ============================

__global__ __launch_bounds__(256) void k1_nodeF(const float* __restrict__ x,
    const float* __restrict__ W1, const float* __restrict__ a1s, const float* __restrict__ a1d,
    float* __restrict__ h1, float* __restrict__ as1, float* __restrict__ ad1, int n)
{
    __shared__ float wt[8 * 128];
    __shared__ float av[16];
    for (int i = threadIdx.x; i < 1024; i += 256) {
        int r = i >> 3, k = i & 7;
        wt[k * 128 + r] = W1[i];
    }
    if (threadIdx.x < 8)        av[threadIdx.x] = a1s[threadIdx.x];
    else if (threadIdx.x < 16)  av[threadIdx.x] = a1d[threadIdx.x - 8];
    __syncthreads();

    int lane = threadIdx.x & 31;
    int node = blockIdx.x * 8 + (threadIdx.x >> 5);
    if (node >= n) return;

    float4 xv = ((const float4*)(x + (size_t)node * 128))[lane];
    float p[8];
#pragma unroll
    for (int k = 0; k < 8; ++k) {
        float4 wv = ((const float4*)(wt + k * 128))[lane];
        p[k] = xv.x * wv.x + xv.y * wv.y + xv.z * wv.z + xv.w * wv.w;
    }
#pragma unroll
    for (int off = 16; off; off >>= 1)
#pragma unroll
        for (int k = 0; k < 8; ++k) p[k] += __shfl_down(p[k], off, 32);

    if (lane == 0) {
        float s = 0.f, d = 0.f;
#pragma unroll
        for (int k = 0; k < 8; ++k) {
            h1[(size_t)node * 8 + k] = p[k];
            s += p[k] * av[k];
            d += p[k] * av[8 + k];
        }
        as1[node] = s;
        ad1[node] = d;
    }
}

template <int F>
__global__ __launch_bounds__(256) void k_edge(const int* __restrict__ src, const int* __restrict__ dst,
    const float* __restrict__ as, const float* __restrict__ ad, const float* __restrict__ feat,
    float* __restrict__ denom, float* __restrict__ acc, int E)
{
    int e = blockIdx.x * 256 + threadIdx.x;
    if (e >= E) return;
    int s = src[e], d = dst[e];
    float t = as[s] + ad[d];
    float w = __expf(t > 0.f ? t : NEG * t);
    atomicAdd(denom + d, w);
    const float* fs = feat + (size_t)s * F;
    float* ac = acc + (size_t)d * F;
#pragma unroll
    for (int k = 0; k < F; ++k) atomicAdd(ac + k, w * fs[k]);
}

__global__ __launch_bounds__(256) void k3_node(const float* __restrict__ denom1,
    const float* __restrict__ acc1, const float* __restrict__ b1,
    const float* __restrict__ W2, const float* __restrict__ a2s, const float* __restrict__ a2d,
    float* __restrict__ g, float* __restrict__ as2, float* __restrict__ ad2, int n)
{
    __shared__ float w2[128];
    __shared__ float aa[32];
    __shared__ float bb[8];
    if (threadIdx.x < 128) w2[threadIdx.x] = W2[threadIdx.x];
    if (threadIdx.x >= 128 && threadIdx.x < 144) aa[threadIdx.x - 128] = a2s[threadIdx.x - 128];
    if (threadIdx.x >= 144 && threadIdx.x < 160) aa[16 + threadIdx.x - 144] = a2d[threadIdx.x - 144];
    if (threadIdx.x >= 160 && threadIdx.x < 168) bb[threadIdx.x - 160] = b1[threadIdx.x - 160];
    __syncthreads();

    int node = blockIdx.x * 256 + threadIdx.x;
    if (node >= n) return;
    float dn = denom1[node];
    float inv = dn > 0.f ? 1.f / dn : 0.f;
    float h[8];
#pragma unroll
    for (int k = 0; k < 8; ++k) {
        float v = acc1[(size_t)node * 8 + k] * inv + bb[k];
        h[k] = v > 0.f ? v : 0.f;
    }
    float s = 0.f, dd = 0.f;
#pragma unroll
    for (int c = 0; c < 16; ++c) {
        float gv = 0.f;
#pragma unroll
        for (int k = 0; k < 8; ++k) gv += h[k] * w2[k * 16 + c];
        g[(size_t)node * 16 + c] = gv;
        s += gv * aa[c];
        dd += gv * aa[16 + c];
    }
    as2[node] = s;
    ad2[node] = dd;
}

__global__ __launch_bounds__(256) void k5_final(const float* __restrict__ denom2,
    const float* __restrict__ acc2, const float* __restrict__ b2, float* __restrict__ out, int n)
{
    __shared__ float bb[16];
    if (threadIdx.x < 16) bb[threadIdx.x] = b2[threadIdx.x];
    __syncthreads();

    int node = blockIdx.x * 256 + threadIdx.x;
    if (node >= n) return;
    float dn = denom2[node];
    float inv = dn > 0.f ? 1.f / dn : 0.f;
    float o[16];
    float m = -1e30f;
#pragma unroll
    for (int c = 0; c < 16; ++c) {
        o[c] = acc2[(size_t)node * 16 + c] * inv + bb[c];
        m = fmaxf(m, o[c]);
    }
    float se = 0.f;
#pragma unroll
    for (int c = 0; c < 16; ++c) {
        o[c] -= m;
        se += __expf(o[c]);
    }
    float l = __logf(se);
#pragma unroll
    for (int c = 0; c < 16; ++c) out[(size_t)node * 16 + c] = o[c] - l;
}

// ============================ launch ============================

static inline char* align256(char* p) {
    return (char*)(((uintptr_t)p + 255) & ~(uintptr_t)255);
}

extern "C" void kernel_launch(void* const* d_in, const int* in_sizes, int n_in,
                              void* d_out, int out_size, void* d_ws, size_t ws_size,
                              hipStream_t stream)
{
    const float* x    = (const float*)d_in[0];
    const int*   eidx = (const int*)d_in[1];
    const float* W1   = (const float*)d_in[2];
    const float* a1s  = (const float*)d_in[3];
    const float* a1d  = (const float*)d_in[4];
    const float* b1   = (const float*)d_in[5];
    const float* W2   = (const float*)d_in[6];
    const float* a2s  = (const float*)d_in[7];
    const float* a2d  = (const float*)d_in[8];
    const float* b2   = (const float*)d_in[9];
    float* out = (float*)d_out;

    const int n = in_sizes[0] / 128;
    const int E = in_sizes[1] / 2;
    const int* src = eidx;
    const int* dst = eidx + E;
    const int NB = (n + 255) >> CSHIFT;
    const int NBLK = (E + CHUNK - 1) / CHUNK;

    // ---- tier-0: bucket-sort CSR (gmat/pbaseRel aliased into colsrc) + fp16 gathers ----
    {
        char* p = (char*)d_ws;
        char* p0 = p;
        unsigned* stage = (unsigned*)p;  p = align256(p + (size_t)E * 4);
        int* colsrc  = (int*)p;          p = align256(p + (size_t)E * 4);
        int* total   = (int*)p;          p = align256(p + (size_t)NB * 4);
        int* cptr    = (int*)p;          p = align256(p + (size_t)(NB + 1) * 4);
        int* row_ptr = (int*)p;          p = align256(p + (size_t)(n + 1) * 4);
        __half* h1   = (__half*)p;       p = align256(p + (size_t)8 * n * 2);
        __half* g    = (__half*)p;       p = align256(p + (size_t)16 * n * 2);
        float* as1   = (float*)p;        p = align256(p + (size_t)n * 4);
        float* ad1   = (float*)p;        p = align256(p + (size_t)n * 4);
        float* as2   = (float*)p;        p = align256(p + (size_t)n * 4);
        float* ad2   = (float*)p;        p = align256(p + (size_t)n * 4);
        size_t needed = (size_t)(p - p0);

        int* gmat     = colsrc;                       // alias (dead before p2)
        int* pbaseRel = (int*)align256((char*)(colsrc + (size_t)NBLK * NB));

        bool alias_ok = ((size_t)2 * NBLK * NB + 64) <= (size_t)E;

        if (n <= 131072 && NB <= MAXNB && alias_ok && ws_size >= needed) {
            k1_node<<<(n + 7) / 8, 256, 0, stream>>>(x, W1, a1s, a1d, h1, as1, ad1, n);

            p1a<<<NBLK, 256, 0, stream>>>(dst, gmat, E, NB);
            pcol<<<NB, 256, 0, stream>>>(gmat, pbaseRel, total, NBLK, NB);
            ptot<<<1, 512, 0, stream>>>(total, cptr, row_ptr, NB, n, E);
            p1bM<<<NBLK, 256, 0, stream>>>(src, dst, cptr, pbaseRel, stage, E, NB);
            p2<<<NB, 512, 0, stream>>>(stage, cptr, colsrc, row_ptr, n);

            const int gblocks = (n * 64 + 255) / 256;
            k_gather8f<<<gblocks, 256, 0, stream>>>(row_ptr, colsrc, as1, ad1, h1,
                                                    b1, W2, a2s, a2d, g, as2, ad2, n);
            k_gather16<<<gblocks, 256, 0, stream>>>(row_ptr, colsrc, as2, ad2, g, b2, out, n);
            return;
        }
    }

    // ---- fallback: pure atomic path (fp32) ----
    {
        float* ws     = (float*)d_ws;
        float* denom1 = ws;
        float* acc1   = ws + (size_t)n;
        float* denom2 = ws + (size_t)9 * n;
        float* acc2   = ws + (size_t)10 * n;
        float* h1     = ws + (size_t)26 * n;
        float* as1    = ws + (size_t)34 * n;
        float* ad1    = ws + (size_t)35 * n;
        float* g      = ws + (size_t)36 * n;
        float* as2    = ws + (size_t)52 * n;
        float* ad2    = ws + (size_t)53 * n;

        hipMemsetAsync(ws, 0, (size_t)26 * n * sizeof(float), stream);
        k1_nodeF<<<(n + 7) / 8, 256, 0, stream>>>(x, W1, a1s, a1d, h1, as1, ad1, n);
        k_edge<8><<<(E + 255) / 256, 256, 0, stream>>>(src, dst, as1, ad1, h1, denom1, acc1, E);
        k3_node<<<(n + 255) / 256, 256, 0, stream>>>(denom1, acc1, b1, W2, a2s, a2d, g, as2, ad2, n);
        k_edge<16><<<(E + 255) / 256, 256, 0, stream>>>(src, dst, as2, ad2, g, denom2, acc2, E);
        k5_final<<<(n + 255) / 256, 256, 0, stream>>>(denom2, acc2, b2, out, n);
    }
}

// Round 12
// 321.251 us; speedup vs baseline: 3.8775x; 1.1815x over previous
//
#include <hip/hip_runtime.h>
#include <hip/hip_fp16.h>
#include <math.h>
#include <stdint.h>

#define NEG 0.2f
#define CSHIFT 8
#define MAXNB 512          // supports n <= 131072 (17-bit src pack)
#define CHUNK 2048

// ============================ node transform (fp16 h1 out) ============================

__global__ __launch_bounds__(256) void k1_node(const float* __restrict__ x,
    const float* __restrict__ W1, const float* __restrict__ a1s, const float* __restrict__ a1d,
    __half* __restrict__ h1, float* __restrict__ as1, float* __restrict__ ad1, int n)
{
    __shared__ float wt[8 * 128];
    __shared__ float av[16];
    for (int i = threadIdx.x; i < 1024; i += 256) {
        int r = i >> 3, k = i & 7;
        wt[k * 128 + r] = W1[i];
    }
    if (threadIdx.x < 8)        av[threadIdx.x] = a1s[threadIdx.x];
    else if (threadIdx.x < 16)  av[threadIdx.x] = a1d[threadIdx.x - 8];
    __syncthreads();

    int lane = threadIdx.x & 31;
    int node = blockIdx.x * 8 + (threadIdx.x >> 5);
    if (node >= n) return;

    float4 xv = ((const float4*)(x + (size_t)node * 128))[lane];
    float p[8];
#pragma unroll
    for (int k = 0; k < 8; ++k) {
        float4 wv = ((const float4*)(wt + k * 128))[lane];
        p[k] = xv.x * wv.x + xv.y * wv.y + xv.z * wv.z + xv.w * wv.w;
    }
#pragma unroll
    for (int off = 16; off; off >>= 1)
#pragma unroll
        for (int k = 0; k < 8; ++k) p[k] += __shfl_down(p[k], off, 32);

    if (lane == 0) {
        float s = 0.f, d = 0.f;
        union { float4 f; __half2 h[4]; } u;
#pragma unroll
        for (int k = 0; k < 8; ++k) {
            s += p[k] * av[k];
            d += p[k] * av[8 + k];
        }
#pragma unroll
        for (int q = 0; q < 4; ++q) u.h[q] = __floats2half2_rn(p[2 * q], p[2 * q + 1]);
        ((float4*)h1)[node] = u.f;   // 16B fp16 row
        as1[node] = s;
        ad1[node] = d;
    }
}

// ============================ bucket-sort CSR build (all-parallel, atomic-free) ============================

__global__ __launch_bounds__(256) void p1a(const int* __restrict__ dst, int* __restrict__ gmat,
                                           int E, int NB)
{
    __shared__ int h[MAXNB];
    for (int i = threadIdx.x; i < NB; i += 256) h[i] = 0;
    __syncthreads();
    int base = blockIdx.x * CHUNK;
    int end = base + CHUNK; if (end > E) end = E;
    for (int i = base + threadIdx.x; i < end; i += 256)
        atomicAdd(&h[dst[i] >> CSHIFT], 1);
    __syncthreads();
    int* row = gmat + (size_t)blockIdx.x * NB;
    for (int i = threadIdx.x; i < NB; i += 256) row[i] = h[i];
}

__global__ __launch_bounds__(256) void pcol(const int* __restrict__ gmat, int* __restrict__ pbaseRel,
    int* __restrict__ total, int NBLK, int NB)
{
    __shared__ int wsum[4];
    int b = blockIdx.x;
    int tid = threadIdx.x;
    int chunk = (NBLK + 255) >> 8;
    int k0 = tid * chunk;
    int s = 0;
    for (int j = 0; j < chunk; ++j) {
        int k = k0 + j;
        if (k < NBLK) s += gmat[(size_t)k * NB + b];
    }
    int lane = tid & 63, w = tid >> 6;
    int sc = s;
#pragma unroll
    for (int off = 1; off < 64; off <<= 1) {
        int t = __shfl_up(sc, off, 64);
        if (lane >= off) sc += t;
    }
    if (lane == 63) wsum[w] = sc;
    __syncthreads();
    if (tid == 0) { int a = 0; for (int i = 0; i < 4; ++i) { int t = wsum[i]; wsum[i] = a; a += t; } }
    __syncthreads();
    int run = sc - s + wsum[w];
    for (int j = 0; j < chunk; ++j) {
        int k = k0 + j;
        if (k < NBLK) {
            int gv = gmat[(size_t)k * NB + b];
            pbaseRel[(size_t)k * NB + b] = run;
            run += gv;
        }
    }
    if (tid == 255) total[b] = run;
}

__global__ __launch_bounds__(512) void ptot(const int* __restrict__ total, int* __restrict__ cptr,
                                            int* __restrict__ row_ptr, int NB, int n, int E)
{
    __shared__ int wsum[8];
    int b = threadIdx.x;
    int v = b < NB ? total[b] : 0;
    int lane = b & 63, w = b >> 6;
    int s = v;
#pragma unroll
    for (int off = 1; off < 64; off <<= 1) {
        int t = __shfl_up(s, off, 64);
        if (lane >= off) s += t;
    }
    if (lane == 63) wsum[w] = s;
    __syncthreads();
    if (b == 0) { int a = 0; for (int i = 0; i < 8; ++i) { int t = wsum[i]; wsum[i] = a; a += t; } }
    __syncthreads();
    int excl = s - v + wsum[w];
    if (b < NB) cptr[b] = excl;
    if (b == 0) { cptr[NB] = E; row_ptr[n] = E; }
}

__global__ __launch_bounds__(256) void p1bM(const int* __restrict__ src, const int* __restrict__ dst,
    const int* __restrict__ cptr, const int* __restrict__ pbaseRel, unsigned* __restrict__ stage,
    int E, int NB)
{
    __shared__ int bbase[MAXNB], ccur[MAXNB];
    const int* prow = pbaseRel + (size_t)blockIdx.x * NB;
    for (int i = threadIdx.x; i < NB; i += 256) { bbase[i] = cptr[i] + prow[i]; ccur[i] = 0; }
    __syncthreads();
    int base = blockIdx.x * CHUNK;
    int end = base + CHUNK; if (end > E) end = E;
    for (int i = base + threadIdx.x; i < end; i += 256) {
        int d = dst[i];
        int b = d >> CSHIFT;
        int off = atomicAdd(&ccur[b], 1);
        stage[bbase[b] + off] = ((unsigned)(d & ((1 << CSHIFT) - 1)) << 17) | (unsigned)src[i];
    }
}

__global__ __launch_bounds__(512) void p2(const unsigned* __restrict__ stage,
    const int* __restrict__ cptr, int* __restrict__ colsrc, int* __restrict__ row_ptr, int n)
{
    int b = blockIdx.x;
    int nbase = b << CSHIFT;
    int NN = n - nbase; if (NN > 256) NN = 256;
    __shared__ int h[256], bps[256], cc[256];
    __shared__ int wsum[4];
    int tid = threadIdx.x;
    for (int i = tid; i < 256; i += 512) { h[i] = 0; cc[i] = 0; }
    __syncthreads();
    int s0 = cptr[b], s1 = cptr[b + 1];
    for (int i = s0 + tid; i < s1; i += 512)
        atomicAdd(&h[stage[i] >> 17], 1);
    __syncthreads();
    int v = 0, sc = 0;
    int lane = tid & 63, w = tid >> 6;
    if (tid < 256) {
        v = h[tid];
        sc = v;
#pragma unroll
        for (int off = 1; off < 64; off <<= 1) {
            int t = __shfl_up(sc, off, 64);
            if (lane >= off) sc += t;
        }
        if (lane == 63) wsum[w] = sc;
    }
    __syncthreads();
    if (tid == 0) { int a = 0; for (int i = 0; i < 4; ++i) { int t = wsum[i]; wsum[i] = a; a += t; } }
    __syncthreads();
    if (tid < 256) {
        int excl = sc - v + wsum[w];
        bps[tid] = s0 + excl;
        if (tid < NN) row_ptr[nbase + tid] = s0 + excl;
    }
    __syncthreads();
    for (int i = s0 + tid; i < s1; i += 512) {
        unsigned p = stage[i];
        int f = p >> 17;
        int off = atomicAdd(&cc[f], 1);
        colsrc[bps[f] + off] = (int)(p & 0x1FFFFu);
    }
}

// ============================ gathers (fp16 features, 16 lanes/node, 4 nodes/wave) ============================

// Layer 1 gather + fused layer-2 node transform. h1 fp16 in, g fp16 out.
__global__ __launch_bounds__(256) void k_gather8f(const int* __restrict__ row_ptr,
    const int* __restrict__ colsrc, const float* __restrict__ as, const float* __restrict__ ad,
    const __half* __restrict__ feat, const float* __restrict__ b1,
    const float* __restrict__ W2, const float* __restrict__ a2s, const float* __restrict__ a2d,
    __half* __restrict__ g, float* __restrict__ as2, float* __restrict__ ad2, int n)
{
    __shared__ float w2s[128], a2sv[16], a2dv[16], b1v[8];
    if (threadIdx.x < 128) w2s[threadIdx.x] = W2[threadIdx.x];
    else if (threadIdx.x < 144) a2sv[threadIdx.x - 128] = a2s[threadIdx.x - 128];
    else if (threadIdx.x < 160) a2dv[threadIdx.x - 144] = a2d[threadIdx.x - 144];
    else if (threadIdx.x < 168) b1v[threadIdx.x - 160] = b1[threadIdx.x - 160];
    __syncthreads();

    int wid  = (blockIdx.x * 256 + threadIdx.x) >> 6;
    int lane = threadIdx.x & 63;
    int l16  = lane & 15;
    int node = wid * 4 + (lane >> 4);
    bool active = node < n;

    int start = 0, end = 0;
    float adn = 0.f;
    if (active) { start = row_ptr[node]; end = row_ptr[node + 1]; adn = ad[node]; }

    float wsum = 0.f, acc[8];
#pragma unroll
    for (int k = 0; k < 8; ++k) acc[k] = 0.f;

    for (int i = start + l16; i < end; i += 16) {
        int s = colsrc[i];
        float t = as[s] + adn;
        float w = __expf(t > 0.f ? t : NEG * t);  // max-shift skipped: |t| small, exact ratio
        wsum += w;
        union { float4 fv; __half2 h[4]; } u;
        u.fv = ((const float4*)feat)[s];          // 16B fp16 row
#pragma unroll
        for (int q = 0; q < 4; ++q) {
            float2 hv = __half22float2(u.h[q]);
            acc[2 * q + 0] += w * hv.x;
            acc[2 * q + 1] += w * hv.y;
        }
    }
    // reduce within the 16-lane group (4 levels)
#pragma unroll
    for (int off = 8; off; off >>= 1) {
        wsum += __shfl_xor(wsum, off, 64);
#pragma unroll
        for (int k = 0; k < 8; ++k) acc[k] += __shfl_xor(acc[k], off, 64);
    }
    if (!active) return;

    float inv = wsum > 0.f ? 1.f / wsum : 0.f;
    float h[8];
#pragma unroll
    for (int k = 0; k < 8; ++k) {
        float v = acc[k] * inv + b1v[k];
        h[k] = v > 0.f ? v : 0.f;
    }
    // every lane owns one class c = l16 of its node
    float gv = 0.f;
#pragma unroll
    for (int k = 0; k < 8; ++k) gv += h[k] * w2s[k * 16 + l16];
    float po = __shfl_xor(gv, 1, 64);             // partner class value
    if ((l16 & 1) == 0)
        ((__half2*)(g + (size_t)node * 16))[l16 >> 1] = __floats2half2_rn(gv, po);
    float ps = gv * a2sv[l16];
    float pd = gv * a2dv[l16];
#pragma unroll
    for (int off = 8; off; off >>= 1) {
        ps += __shfl_xor(ps, off, 64);
        pd += __shfl_xor(pd, off, 64);
    }
    if (l16 == 0) { as2[node] = ps; ad2[node] = pd; }
}

// Layer 2 gather with fused log_softmax. g fp16 in.
__global__ __launch_bounds__(256) void k_gather16(const int* __restrict__ row_ptr,
    const int* __restrict__ colsrc, const float* __restrict__ as, const float* __restrict__ ad,
    const __half* __restrict__ feat, const float* __restrict__ bias, float* __restrict__ outp, int n)
{
    __shared__ float bv[16];
    if (threadIdx.x < 16) bv[threadIdx.x] = bias[threadIdx.x];
    __syncthreads();

    int wid  = (blockIdx.x * 256 + threadIdx.x) >> 6;
    int lane = threadIdx.x & 63;
    int l16  = lane & 15;
    int node = wid * 4 + (lane >> 4);
    bool active = node < n;

    int start = 0, end = 0;
    float adn = 0.f;
    if (active) { start = row_ptr[node]; end = row_ptr[node + 1]; adn = ad[node]; }

    float wsum = 0.f, acc[16];
#pragma unroll
    for (int k = 0; k < 16; ++k) acc[k] = 0.f;

    for (int i = start + l16; i < end; i += 16) {
        int s = colsrc[i];
        float t = as[s] + adn;
        float w = __expf(t > 0.f ? t : NEG * t);
        wsum += w;
        union { float4 fv[2]; __half2 h[8]; } u;
        const float4* gs = (const float4*)(feat + (size_t)s * 16);  // 32B fp16 row
        u.fv[0] = gs[0];
        u.fv[1] = gs[1];
#pragma unroll
        for (int q = 0; q < 8; ++q) {
            float2 gv = __half22float2(u.h[q]);
            acc[2 * q + 0] += w * gv.x;
            acc[2 * q + 1] += w * gv.y;
        }
    }
    // reduce within the 16-lane group (4 levels)
#pragma unroll
    for (int off = 8; off; off >>= 1) {
        wsum += __shfl_xor(wsum, off, 64);
#pragma unroll
        for (int k = 0; k < 16; ++k) acc[k] += __shfl_xor(acc[k], off, 64);
    }
    if (!active) return;

    float inv = wsum > 0.f ? 1.f / wsum : 0.f;
    float o[16], m = -1e30f;
#pragma unroll
    for (int c = 0; c < 16; ++c) {
        o[c] = acc[c] * inv + bv[c];
        m = fmaxf(m, o[c]);
    }
    float se = 0.f;
#pragma unroll
    for (int c = 0; c < 16; ++c) se += __expf(o[c] - m);
    float l = m + __logf(se);
    outp[(size_t)node * 16 + l16] = o[l16] - l;   // 4 consecutive 64B rows per wave
}

// ============================ fallback: pure atomic path (fp32) ============================

__global__ __launch_bounds__(256) void k1_nodeF(const float* __restrict__ x,
    const float* __restrict__ W1, const float* __restrict__ a1s, const float* __restrict__ a1d,
    float* __restrict__ h1, float* __restrict__ as1, float* __restrict__ ad1, int n)
{
    __shared__ float wt[8 * 128];
    __shared__ float av[16];
    for (int i = threadIdx.x; i < 1024; i += 256) {
        int r = i >> 3, k = i & 7;
        wt[k * 128 + r] = W1[i];
    }
    if (threadIdx.x < 8)        av[threadIdx.x] = a1s[threadIdx.x];
    else if (threadIdx.x < 16)  av[threadIdx.x] = a1d[threadIdx.x - 8];
    __syncthreads();

    int lane = threadIdx.x & 31;
    int node = blockIdx.x * 8 + (threadIdx.x >> 5);
    if (node >= n) return;

    float4 xv = ((const float4*)(x + (size_t)node * 128))[lane];
    float p[8];
#pragma unroll
    for (int k = 0; k < 8; ++k) {
        float4 wv = ((const float4*)(wt + k * 128))[lane];
        p[k] = xv.x * wv.x + xv.y * wv.y + xv.z * wv.z + xv.w * wv.w;
    }
#pragma unroll
    for (int off = 16; off; off >>= 1)
#pragma unroll
        for (int k = 0; k < 8; ++k) p[k] += __shfl_down(p[k], off, 32);

    if (lane == 0) {
        float s = 0.f, d = 0.f;
#pragma unroll
        for (int k = 0; k < 8; ++k) {
            h1[(size_t)node * 8 + k] = p[k];
            s += p[k] * av[k];
            d += p[k] * av[8 + k];
        }
        as1[node] = s;
        ad1[node] = d;
    }
}

template <int F>
__global__ __launch_bounds__(256) void k_edge(const int* __restrict__ src, const int* __restrict__ dst,
    const float* __restrict__ as, const float* __restrict__ ad, const float* __restrict__ feat,
    float* __restrict__ denom, float* __restrict__ acc, int E)
{
    int e = blockIdx.x * 256 + threadIdx.x;
    if (e >= E) return;
    int s = src[e], d = dst[e];
    float t = as[s] + ad[d];
    float w = __expf(t > 0.f ? t : NEG * t);
    atomicAdd(denom + d, w);
    const float* fs = feat + (size_t)s * F;
    float* ac = acc + (size_t)d * F;
#pragma unroll
    for (int k = 0; k < F; ++k) atomicAdd(ac + k, w * fs[k]);
}

__global__ __launch_bounds__(256) void k3_node(const float* __restrict__ denom1,
    const float* __restrict__ acc1, const float* __restrict__ b1,
    const float* __restrict__ W2, const float* __restrict__ a2s, const float* __restrict__ a2d,
    float* __restrict__ g, float* __restrict__ as2, float* __restrict__ ad2, int n)
{
    __shared__ float w2[128];
    __shared__ float aa[32];
    __shared__ float bb[8];
    if (threadIdx.x < 128) w2[threadIdx.x] = W2[threadIdx.x];
    if (threadIdx.x >= 128 && threadIdx.x < 144) aa[threadIdx.x - 128] = a2s[threadIdx.x - 128];
    if (threadIdx.x >= 144 && threadIdx.x < 160) aa[16 + threadIdx.x - 144] = a2d[threadIdx.x - 144];
    if (threadIdx.x >= 160 && threadIdx.x < 168) bb[threadIdx.x - 160] = b1[threadIdx.x - 160];
    __syncthreads();

    int node = blockIdx.x * 256 + threadIdx.x;
    if (node >= n) return;
    float dn = denom1[node];
    float inv = dn > 0.f ? 1.f / dn : 0.f;
    float h[8];
#pragma unroll
    for (int k = 0; k < 8; ++k) {
        float v = acc1[(size_t)node * 8 + k] * inv + bb[k];
        h[k] = v > 0.f ? v : 0.f;
    }
    float s = 0.f, dd = 0.f;
#pragma unroll
    for (int c = 0; c < 16; ++c) {
        float gv = 0.f;
#pragma unroll
        for (int k = 0; k < 8; ++k) gv += h[k] * w2[k * 16 + c];
        g[(size_t)node * 16 + c] = gv;
        s += gv * aa[c];
        dd += gv * aa[16 + c];
    }
    as2[node] = s;
    ad2[node] = dd;
}

__global__ __launch_bounds__(256) void k5_final(const float* __restrict__ denom2,
    const float* __restrict__ acc2, const float* __restrict__ b2, float* __restrict__ out, int n)
{
    __shared__ float bb[16];
    if (threadIdx.x < 16) bb[threadIdx.x] = b2[threadIdx.x];
    __syncthreads();

    int node = blockIdx.x * 256 + threadIdx.x;
    if (node >= n) return;
    float dn = denom2[node];
    float inv = dn > 0.f ? 1.f / dn : 0.f;
    float o[16];
    float m = -1e30f;
#pragma unroll
    for (int c = 0; c < 16; ++c) {
        o[c] = acc2[(size_t)node * 16 + c] * inv + bb[c];
        m = fmaxf(m, o[c]);
    }
    float se = 0.f;
#pragma unroll
    for (int c = 0; c < 16; ++c) {
        o[c] -= m;
        se += __expf(o[c]);
    }
    float l = __logf(se);
#pragma unroll
    for (int c = 0; c < 16; ++c) out[(size_t)node * 16 + c] = o[c] - l;
}

// ============================ launch ============================

static inline char* align256(char* p) {
    return (char*)(((uintptr_t)p + 255) & ~(uintptr_t)255);
}

extern "C" void kernel_launch(void* const* d_in, const int* in_sizes, int n_in,
                              void* d_out, int out_size, void* d_ws, size_t ws_size,
                              hipStream_t stream)
{
    const float* x    = (const float*)d_in[0];
    const int*   eidx = (const int*)d_in[1];
    const float* W1   = (const float*)d_in[2];
    const float* a1s  = (const float*)d_in[3];
    const float* a1d  = (const float*)d_in[4];
    const float* b1   = (const float*)d_in[5];
    const float* W2   = (const float*)d_in[6];
    const float* a2s  = (const float*)d_in[7];
    const float* a2d  = (const float*)d_in[8];
    const float* b2   = (const float*)d_in[9];
    float* out = (float*)d_out;

    const int n = in_sizes[0] / 128;
    const int E = in_sizes[1] / 2;
    const int* src = eidx;
    const int* dst = eidx + E;
    const int NB = (n + 255) >> CSHIFT;
    const int NBLK = (E + CHUNK - 1) / CHUNK;

    // ---- tier-0: bucket-sort CSR (gmat/pbaseRel aliased into colsrc) + fp16 gathers ----
    {
        char* p = (char*)d_ws;
        char* p0 = p;
        unsigned* stage = (unsigned*)p;  p = align256(p + (size_t)E * 4);
        int* colsrc  = (int*)p;          p = align256(p + (size_t)E * 4);
        int* total   = (int*)p;          p = align256(p + (size_t)NB * 4);
        int* cptr    = (int*)p;          p = align256(p + (size_t)(NB + 1) * 4);
        int* row_ptr = (int*)p;          p = align256(p + (size_t)(n + 1) * 4);
        __half* h1   = (__half*)p;       p = align256(p + (size_t)8 * n * 2);
        __half* g    = (__half*)p;       p = align256(p + (size_t)16 * n * 2);
        float* as1   = (float*)p;        p = align256(p + (size_t)n * 4);
        float* ad1   = (float*)p;        p = align256(p + (size_t)n * 4);
        float* as2   = (float*)p;        p = align256(p + (size_t)n * 4);
        float* ad2   = (float*)p;        p = align256(p + (size_t)n * 4);
        size_t needed = (size_t)(p - p0);

        int* gmat     = colsrc;                       // alias (dead before p2)
        int* pbaseRel = (int*)align256((char*)(colsrc + (size_t)NBLK * NB));

        bool alias_ok = ((size_t)2 * NBLK * NB + 64) <= (size_t)E;

        if (n <= 131072 && NB <= MAXNB && alias_ok && ws_size >= needed) {
            k1_node<<<(n + 7) / 8, 256, 0, stream>>>(x, W1, a1s, a1d, h1, as1, ad1, n);

            p1a<<<NBLK, 256, 0, stream>>>(dst, gmat, E, NB);
            pcol<<<NB, 256, 0, stream>>>(gmat, pbaseRel, total, NBLK, NB);
            ptot<<<1, 512, 0, stream>>>(total, cptr, row_ptr, NB, n, E);
            p1bM<<<NBLK, 256, 0, stream>>>(src, dst, cptr, pbaseRel, stage, E, NB);
            p2<<<NB, 512, 0, stream>>>(stage, cptr, colsrc, row_ptr, n);

            // 16 lanes per node, 4 nodes per wave
            const int gblocks = ((size_t)n * 16 + 255) / 256;
            k_gather8f<<<gblocks, 256, 0, stream>>>(row_ptr, colsrc, as1, ad1, h1,
                                                    b1, W2, a2s, a2d, g, as2, ad2, n);
            k_gather16<<<gblocks, 256, 0, stream>>>(row_ptr, colsrc, as2, ad2, g, b2, out, n);
            return;
        }
    }

    // ---- fallback: pure atomic path (fp32) ----
    {
        float* ws     = (float*)d_ws;
        float* denom1 = ws;
        float* acc1   = ws + (size_t)n;
        float* denom2 = ws + (size_t)9 * n;
        float* acc2   = ws + (size_t)10 * n;
        float* h1     = ws + (size_t)26 * n;
        float* as1    = ws + (size_t)34 * n;
        float* ad1    = ws + (size_t)35 * n;
        float* g      = ws + (size_t)36 * n;
        float* as2    = ws + (size_t)52 * n;
        float* ad2    = ws + (size_t)53 * n;

        hipMemsetAsync(ws, 0, (size_t)26 * n * sizeof(float), stream);
        k1_nodeF<<<(n + 7) / 8, 256, 0, stream>>>(x, W1, a1s, a1d, h1, as1, ad1, n);
        k_edge<8><<<(E + 255) / 256, 256, 0, stream>>>(src, dst, as1, ad1, h1, denom1, acc1, E);
        k3_node<<<(n + 255) / 256, 256, 0, stream>>>(denom1, acc1, b1, W2, a2s, a2d, g, as2, ad2, n);
        k_edge<16><<<(E + 255) / 256, 256, 0, stream>>>(src, dst, as2, ad2, g, denom2, acc2, E);
        k5_final<<<(n + 255) / 256, 256, 0, stream>>>(denom2, acc2, b2, out, n);
    }
}

// Round 13
// 296.019 us; speedup vs baseline: 4.2079x; 1.0852x over previous
//
#include <hip/hip_runtime.h>
#include <hip/hip_fp16.h>
#include <math.h>
#include <stdint.h>

#define NEG 0.2f
#define CSHIFT 9
#define BUCKN (1 << CSHIFT)     // 512 nodes per bucket
#define MAXNB 512               // supports n <= 131072 (17-bit src pack)
#define CHUNK 4096

// ============================ node transform (fp16 h1 out) ============================

__global__ __launch_bounds__(256) void k1_node(const float* __restrict__ x,
    const float* __restrict__ W1, const float* __restrict__ a1s, const float* __restrict__ a1d,
    __half* __restrict__ h1, float* __restrict__ as1, float* __restrict__ ad1, int n)
{
    __shared__ float wt[8 * 128];
    __shared__ float av[16];
    for (int i = threadIdx.x; i < 1024; i += 256) {
        int r = i >> 3, k = i & 7;
        wt[k * 128 + r] = W1[i];
    }
    if (threadIdx.x < 8)        av[threadIdx.x] = a1s[threadIdx.x];
    else if (threadIdx.x < 16)  av[threadIdx.x] = a1d[threadIdx.x - 8];
    __syncthreads();

    int lane = threadIdx.x & 31;
    int node = blockIdx.x * 8 + (threadIdx.x >> 5);
    if (node >= n) return;

    float4 xv = ((const float4*)(x + (size_t)node * 128))[lane];
    float p[8];
#pragma unroll
    for (int k = 0; k < 8; ++k) {
        float4 wv = ((const float4*)(wt + k * 128))[lane];
        p[k] = xv.x * wv.x + xv.y * wv.y + xv.z * wv.z + xv.w * wv.w;
    }
#pragma unroll
    for (int off = 16; off; off >>= 1)
#pragma unroll
        for (int k = 0; k < 8; ++k) p[k] += __shfl_down(p[k], off, 32);

    if (lane == 0) {
        float s = 0.f, d = 0.f;
        union { float4 f; __half2 h[4]; } u;
#pragma unroll
        for (int k = 0; k < 8; ++k) {
            s += p[k] * av[k];
            d += p[k] * av[8 + k];
        }
#pragma unroll
        for (int q = 0; q < 4; ++q) u.h[q] = __floats2half2_rn(p[2 * q], p[2 * q + 1]);
        ((float4*)h1)[node] = u.f;   // 16B fp16 row
        as1[node] = s;
        ad1[node] = d;
    }
}

// ============================ bucket-sort CSR build (all-parallel, atomic-free) ============================

__global__ __launch_bounds__(256) void p1a(const int* __restrict__ dst, int* __restrict__ gmat,
                                           int E, int NB)
{
    __shared__ int h[MAXNB];
    for (int i = threadIdx.x; i < NB; i += 256) h[i] = 0;
    __syncthreads();
    int base = blockIdx.x * CHUNK;
    int end = base + CHUNK; if (end > E) end = E;
    for (int i = base + threadIdx.x; i < end; i += 256)
        atomicAdd(&h[dst[i] >> CSHIFT], 1);
    __syncthreads();
    int* row = gmat + (size_t)blockIdx.x * NB;
    for (int i = threadIdx.x; i < NB; i += 256) row[i] = h[i];
}

__global__ __launch_bounds__(256) void pcol(const int* __restrict__ gmat, int* __restrict__ pbaseRel,
    int* __restrict__ total, int NBLK, int NB)
{
    __shared__ int wsum[4];
    int b = blockIdx.x;
    int tid = threadIdx.x;
    int chunk = (NBLK + 255) >> 8;
    int k0 = tid * chunk;
    int s = 0;
    for (int j = 0; j < chunk; ++j) {
        int k = k0 + j;
        if (k < NBLK) s += gmat[(size_t)k * NB + b];
    }
    int lane = tid & 63, w = tid >> 6;
    int sc = s;
#pragma unroll
    for (int off = 1; off < 64; off <<= 1) {
        int t = __shfl_up(sc, off, 64);
        if (lane >= off) sc += t;
    }
    if (lane == 63) wsum[w] = sc;
    __syncthreads();
    if (tid == 0) { int a = 0; for (int i = 0; i < 4; ++i) { int t = wsum[i]; wsum[i] = a; a += t; } }
    __syncthreads();
    int run = sc - s + wsum[w];
    for (int j = 0; j < chunk; ++j) {
        int k = k0 + j;
        if (k < NBLK) {
            int gv = gmat[(size_t)k * NB + b];
            pbaseRel[(size_t)k * NB + b] = run;
            run += gv;
        }
    }
    if (tid == 255) total[b] = run;
}

__global__ __launch_bounds__(512) void ptot(const int* __restrict__ total, int* __restrict__ cptr,
                                            int* __restrict__ row_ptr, int NB, int n, int E)
{
    __shared__ int wsum[8];
    int b = threadIdx.x;
    int v = b < NB ? total[b] : 0;
    int lane = b & 63, w = b >> 6;
    int s = v;
#pragma unroll
    for (int off = 1; off < 64; off <<= 1) {
        int t = __shfl_up(s, off, 64);
        if (lane >= off) s += t;
    }
    if (lane == 63) wsum[w] = s;
    __syncthreads();
    if (b == 0) { int a = 0; for (int i = 0; i < 8; ++i) { int t = wsum[i]; wsum[i] = a; a += t; } }
    __syncthreads();
    int excl = s - v + wsum[w];
    if (b < NB) cptr[b] = excl;
    if (b == 0) { cptr[NB] = E; row_ptr[n] = E; }
}

__global__ __launch_bounds__(256) void p1bM(const int* __restrict__ src, const int* __restrict__ dst,
    const int* __restrict__ cptr, const int* __restrict__ pbaseRel, unsigned* __restrict__ stage,
    int E, int NB)
{
    __shared__ int bbase[MAXNB], ccur[MAXNB];
    const int* prow = pbaseRel + (size_t)blockIdx.x * NB;
    for (int i = threadIdx.x; i < NB; i += 256) { bbase[i] = cptr[i] + prow[i]; ccur[i] = 0; }
    __syncthreads();
    int base = blockIdx.x * CHUNK;
    int end = base + CHUNK; if (end > E) end = E;
    for (int i = base + threadIdx.x; i < end; i += 256) {
        int d = dst[i];
        int b = d >> CSHIFT;
        int off = atomicAdd(&ccur[b], 1);
        stage[bbase[b] + off] = ((unsigned)(d & (BUCKN - 1)) << 17) | (unsigned)src[i];
    }
}

// pass 2: per-bucket fine counting-sort (512-node buckets) -> colsrc + row_ptr
__global__ __launch_bounds__(512) void p2(const unsigned* __restrict__ stage,
    const int* __restrict__ cptr, int* __restrict__ colsrc, int* __restrict__ row_ptr, int n)
{
    int b = blockIdx.x;
    int nbase = b << CSHIFT;
    int NN = n - nbase; if (NN > BUCKN) NN = BUCKN;
    __shared__ int h[BUCKN], bps[BUCKN], cc[BUCKN];
    __shared__ int wsum[8];
    int tid = threadIdx.x;
    h[tid] = 0; cc[tid] = 0;
    __syncthreads();
    int s0 = cptr[b], s1 = cptr[b + 1];
    for (int i = s0 + tid; i < s1; i += 512)
        atomicAdd(&h[stage[i] >> 17], 1);
    __syncthreads();
    int v = h[tid];
    int lane = tid & 63, w = tid >> 6;
    int sc = v;
#pragma unroll
    for (int off = 1; off < 64; off <<= 1) {
        int t = __shfl_up(sc, off, 64);
        if (lane >= off) sc += t;
    }
    if (lane == 63) wsum[w] = sc;
    __syncthreads();
    if (tid == 0) { int a = 0; for (int i = 0; i < 8; ++i) { int t = wsum[i]; wsum[i] = a; a += t; } }
    __syncthreads();
    int excl = sc - v + wsum[w];
    bps[tid] = s0 + excl;
    if (tid < NN) row_ptr[nbase + tid] = s0 + excl;
    __syncthreads();
    for (int i = s0 + tid; i < s1; i += 512) {
        unsigned p = stage[i];
        int f = p >> 17;
        int off = atomicAdd(&cc[f], 1);
        colsrc[bps[f] + off] = (int)(p & 0x1FFFFu);
    }
}

// ============================ gathers (fp16 features, 16 lanes/node, 4 nodes/wave) ============================

__global__ __launch_bounds__(256) void k_gather8f(const int* __restrict__ row_ptr,
    const int* __restrict__ colsrc, const float* __restrict__ as, const float* __restrict__ ad,
    const __half* __restrict__ feat, const float* __restrict__ b1,
    const float* __restrict__ W2, const float* __restrict__ a2s, const float* __restrict__ a2d,
    __half* __restrict__ g, float* __restrict__ as2, float* __restrict__ ad2, int n)
{
    __shared__ float w2s[128], a2sv[16], a2dv[16], b1v[8];
    if (threadIdx.x < 128) w2s[threadIdx.x] = W2[threadIdx.x];
    else if (threadIdx.x < 144) a2sv[threadIdx.x - 128] = a2s[threadIdx.x - 128];
    else if (threadIdx.x < 160) a2dv[threadIdx.x - 144] = a2d[threadIdx.x - 144];
    else if (threadIdx.x < 168) b1v[threadIdx.x - 160] = b1[threadIdx.x - 160];
    __syncthreads();

    int wid  = (blockIdx.x * 256 + threadIdx.x) >> 6;
    int lane = threadIdx.x & 63;
    int l16  = lane & 15;
    int node = wid * 4 + (lane >> 4);
    bool active = node < n;

    int start = 0, end = 0;
    float adn = 0.f;
    if (active) { start = row_ptr[node]; end = row_ptr[node + 1]; adn = ad[node]; }

    float wsum = 0.f, acc[8];
#pragma unroll
    for (int k = 0; k < 8; ++k) acc[k] = 0.f;

    for (int i = start + l16; i < end; i += 16) {
        int s = colsrc[i];
        float t = as[s] + adn;
        float w = __expf(t > 0.f ? t : NEG * t);  // max-shift skipped: |t| small, exact ratio
        wsum += w;
        union { float4 fv; __half2 h[4]; } u;
        u.fv = ((const float4*)feat)[s];          // 16B fp16 row
#pragma unroll
        for (int q = 0; q < 4; ++q) {
            float2 hv = __half22float2(u.h[q]);
            acc[2 * q + 0] += w * hv.x;
            acc[2 * q + 1] += w * hv.y;
        }
    }
#pragma unroll
    for (int off = 8; off; off >>= 1) {
        wsum += __shfl_xor(wsum, off, 64);
#pragma unroll
        for (int k = 0; k < 8; ++k) acc[k] += __shfl_xor(acc[k], off, 64);
    }
    if (!active) return;

    float inv = wsum > 0.f ? 1.f / wsum : 0.f;
    float h[8];
#pragma unroll
    for (int k = 0; k < 8; ++k) {
        float v = acc[k] * inv + b1v[k];
        h[k] = v > 0.f ? v : 0.f;
    }
    float gv = 0.f;
#pragma unroll
    for (int k = 0; k < 8; ++k) gv += h[k] * w2s[k * 16 + l16];
    float po = __shfl_xor(gv, 1, 64);
    if ((l16 & 1) == 0)
        ((__half2*)(g + (size_t)node * 16))[l16 >> 1] = __floats2half2_rn(gv, po);
    float ps = gv * a2sv[l16];
    float pd = gv * a2dv[l16];
#pragma unroll
    for (int off = 8; off; off >>= 1) {
        ps += __shfl_xor(ps, off, 64);
        pd += __shfl_xor(pd, off, 64);
    }
    if (l16 == 0) { as2[node] = ps; ad2[node] = pd; }
}

__global__ __launch_bounds__(256) void k_gather16(const int* __restrict__ row_ptr,
    const int* __restrict__ colsrc, const float* __restrict__ as, const float* __restrict__ ad,
    const __half* __restrict__ feat, const float* __restrict__ bias, float* __restrict__ outp, int n)
{
    __shared__ float bv[16];
    if (threadIdx.x < 16) bv[threadIdx.x] = bias[threadIdx.x];
    __syncthreads();

    int wid  = (blockIdx.x * 256 + threadIdx.x) >> 6;
    int lane = threadIdx.x & 63;
    int l16  = lane & 15;
    int node = wid * 4 + (lane >> 4);
    bool active = node < n;

    int start = 0, end = 0;
    float adn = 0.f;
    if (active) { start = row_ptr[node]; end = row_ptr[node + 1]; adn = ad[node]; }

    float wsum = 0.f, acc[16];
#pragma unroll
    for (int k = 0; k < 16; ++k) acc[k] = 0.f;

    for (int i = start + l16; i < end; i += 16) {
        int s = colsrc[i];
        float t = as[s] + adn;
        float w = __expf(t > 0.f ? t : NEG * t);
        wsum += w;
        union { float4 fv[2]; __half2 h[8]; } u;
        const float4* gs = (const float4*)(feat + (size_t)s * 16);  // 32B fp16 row
        u.fv[0] = gs[0];
        u.fv[1] = gs[1];
#pragma unroll
        for (int q = 0; q < 8; ++q) {
            float2 gv = __half22float2(u.h[q]);
            acc[2 * q + 0] += w * gv.x;
            acc[2 * q + 1] += w * gv.y;
        }
    }
#pragma unroll
    for (int off = 8; off; off >>= 1) {
        wsum += __shfl_xor(wsum, off, 64);
#pragma unroll
        for (int k = 0; k < 16; ++k) acc[k] += __shfl_xor(acc[k], off, 64);
    }
    if (!active) return;

    float inv = wsum > 0.f ? 1.f / wsum : 0.f;
    float o[16], m = -1e30f;
#pragma unroll
    for (int c = 0; c < 16; ++c) {
        o[c] = acc[c] * inv + bv[c];
        m = fmaxf(m, o[c]);
    }
    float se = 0.f;
#pragma unroll
    for (int c = 0; c < 16; ++c) se += __expf(o[c] - m);
    float l = m + __logf(se);
    outp[(size_t)node * 16 + l16] = o[l16] - l;
}

// ============================ fallback: pure atomic path (fp32) ============================

__global__ __launch_bounds__(256) void k1_nodeF(const float* __restrict__ x,
    const float* __restrict__ W1, const float* __restrict__ a1s, const float* __restrict__ a1d,
    float* __restrict__ h1, float* __restrict__ as1, float* __restrict__ ad1, int n)
{
    __shared__ float wt[8 * 128];
    __shared__ float av[16];
    for (int i = threadIdx.x; i < 1024; i += 256) {
        int r = i >> 3, k = i & 7;
        wt[k * 128 + r] = W1[i];
    }
    if (threadIdx.x < 8)        av[threadIdx.x] = a1s[threadIdx.x];
    else if (threadIdx.x < 16)  av[threadIdx.x] = a1d[threadIdx.x - 8];
    __syncthreads();

    int lane = threadIdx.x & 31;
    int node = blockIdx.x * 8 + (threadIdx.x >> 5);
    if (node >= n) return;

    float4 xv = ((const float4*)(x + (size_t)node * 128))[lane];
    float p[8];
#pragma unroll
    for (int k = 0; k < 8; ++k) {
        float4 wv = ((const float4*)(wt + k * 128))[lane];
        p[k] = xv.x * wv.x + xv.y * wv.y + xv.z * wv.z + xv.w * wv.w;
    }
#pragma unroll
    for (int off = 16; off; off >>= 1)
#pragma unroll
        for (int k = 0; k < 8; ++k) p[k] += __shfl_down(p[k], off, 32);

    if (lane == 0) {
        float s = 0.f, d = 0.f;
#pragma unroll
        for (int k = 0; k < 8; ++k) {
            h1[(size_t)node * 8 + k] = p[k];
            s += p[k] * av[k];
            d += p[k] * av[8 + k];
        }
        as1[node] = s;
        ad1[node] = d;
    }
}

template <int F>
__global__ __launch_bounds__(256) void k_edge(const int* __restrict__ src, const int* __restrict__ dst,
    const float* __restrict__ as, const float* __restrict__ ad, const float* __restrict__ feat,
    float* __restrict__ denom, float* __restrict__ acc, int E)
{
    int e = blockIdx.x * 256 + threadIdx.x;
    if (e >= E) return;
    int s = src[e], d = dst[e];
    float t = as[s] + ad[d];
    float w = __expf(t > 0.f ? t : NEG * t);
    atomicAdd(denom + d, w);
    const float* fs = feat + (size_t)s * F;
    float* ac = acc + (size_t)d * F;
#pragma unroll
    for (int k = 0; k < F; ++k) atomicAdd(ac + k, w * fs[k]);
}

__global__ __launch_bounds__(256) void k3_node(const float* __restrict__ denom1,
    const float* __restrict__ acc1, const float* __restrict__ b1,
    const float* __restrict__ W2, const float* __restrict__ a2s, const float* __restrict__ a2d,
    float* __restrict__ g, float* __restrict__ as2, float* __restrict__ ad2, int n)
{
    __shared__ float w2[128];
    __shared__ float aa[32];
    __shared__ float bb[8];
    if (threadIdx.x < 128) w2[threadIdx.x] = W2[threadIdx.x];
    if (threadIdx.x >= 128 && threadIdx.x < 144) aa[threadIdx.x - 128] = a2s[threadIdx.x - 128];
    if (threadIdx.x >= 144 && threadIdx.x < 160) aa[16 + threadIdx.x - 144] = a2d[threadIdx.x - 144];
    if (threadIdx.x >= 160 && threadIdx.x < 168) bb[threadIdx.x - 160] = b1[threadIdx.x - 160];
    __syncthreads();

    int node = blockIdx.x * 256 + threadIdx.x;
    if (node >= n) return;
    float dn = denom1[node];
    float inv = dn > 0.f ? 1.f / dn : 0.f;
    float h[8];
#pragma unroll
    for (int k = 0; k < 8; ++k) {
        float v = acc1[(size_t)node * 8 + k] * inv + bb[k];
        h[k] = v > 0.f ? v : 0.f;
    }
    float s = 0.f, dd = 0.f;
#pragma unroll
    for (int c = 0; c < 16; ++c) {
        float gv = 0.f;
#pragma unroll
        for (int k = 0; k < 8; ++k) gv += h[k] * w2[k * 16 + c];
        g[(size_t)node * 16 + c] = gv;
        s += gv * aa[c];
        dd += gv * aa[16 + c];
    }
    as2[node] = s;
    ad2[node] = dd;
}

__global__ __launch_bounds__(256) void k5_final(const float* __restrict__ denom2,
    const float* __restrict__ acc2, const float* __restrict__ b2, float* __restrict__ out, int n)
{
    __shared__ float bb[16];
    if (threadIdx.x < 16) bb[threadIdx.x] = b2[threadIdx.x];
    __syncthreads();

    int node = blockIdx.x * 256 + threadIdx.x;
    if (node >= n) return;
    float dn = denom2[node];
    float inv = dn > 0.f ? 1.f / dn : 0.f;
    float o[16];
    float m = -1e30f;
#pragma unroll
    for (int c = 0; c < 16; ++c) {
        o[c] = acc2[(size_t)node * 16 + c] * inv + bb[c];
        m = fmaxf(m, o[c]);
    }
    float se = 0.f;
#pragma unroll
    for (int c = 0; c < 16; ++c) {
        o[c] -= m;
        se += __expf(o[c]);
    }
    float l = __logf(se);
#pragma unroll
    for (int c = 0; c < 16; ++c) out[(size_t)node * 16 + c] = o[c] - l;
}

// ============================ launch ============================

static inline char* align256(char* p) {
    return (char*)(((uintptr_t)p + 255) & ~(uintptr_t)255);
}

extern "C" void kernel_launch(void* const* d_in, const int* in_sizes, int n_in,
                              void* d_out, int out_size, void* d_ws, size_t ws_size,
                              hipStream_t stream)
{
    const float* x    = (const float*)d_in[0];
    const int*   eidx = (const int*)d_in[1];
    const float* W1   = (const float*)d_in[2];
    const float* a1s  = (const float*)d_in[3];
    const float* a1d  = (const float*)d_in[4];
    const float* b1   = (const float*)d_in[5];
    const float* W2   = (const float*)d_in[6];
    const float* a2s  = (const float*)d_in[7];
    const float* a2d  = (const float*)d_in[8];
    const float* b2   = (const float*)d_in[9];
    float* out = (float*)d_out;

    const int n = in_sizes[0] / 128;
    const int E = in_sizes[1] / 2;
    const int* src = eidx;
    const int* dst = eidx + E;
    const int NB = (n + BUCKN - 1) >> CSHIFT;
    const int NBLK = (E + CHUNK - 1) / CHUNK;

    // ---- tier-0: bucket-sort CSR (gmat/pbaseRel aliased into colsrc) + fp16 gathers ----
    {
        char* p = (char*)d_ws;
        char* p0 = p;
        unsigned* stage = (unsigned*)p;  p = align256(p + (size_t)E * 4);
        int* colsrc  = (int*)p;          p = align256(p + (size_t)E * 4);
        int* total   = (int*)p;          p = align256(p + (size_t)NB * 4);
        int* cptr    = (int*)p;          p = align256(p + (size_t)(NB + 1) * 4);
        int* row_ptr = (int*)p;          p = align256(p + (size_t)(n + 1) * 4);
        __half* h1   = (__half*)p;       p = align256(p + (size_t)8 * n * 2);
        __half* g    = (__half*)p;       p = align256(p + (size_t)16 * n * 2);
        float* as1   = (float*)p;        p = align256(p + (size_t)n * 4);
        float* ad1   = (float*)p;        p = align256(p + (size_t)n * 4);
        float* as2   = (float*)p;        p = align256(p + (size_t)n * 4);
        float* ad2   = (float*)p;        p = align256(p + (size_t)n * 4);
        size_t needed = (size_t)(p - p0);

        int* gmat     = colsrc;                       // alias (dead before p2)
        int* pbaseRel = (int*)align256((char*)(colsrc + (size_t)NBLK * NB));

        bool alias_ok = ((size_t)2 * NBLK * NB + 64) <= (size_t)E;

        if (n <= 131072 && NB <= MAXNB && alias_ok && ws_size >= needed) {
            k1_node<<<(n + 7) / 8, 256, 0, stream>>>(x, W1, a1s, a1d, h1, as1, ad1, n);

            p1a<<<NBLK, 256, 0, stream>>>(dst, gmat, E, NB);
            pcol<<<NB, 256, 0, stream>>>(gmat, pbaseRel, total, NBLK, NB);
            ptot<<<1, 512, 0, stream>>>(total, cptr, row_ptr, NB, n, E);
            p1bM<<<NBLK, 256, 0, stream>>>(src, dst, cptr, pbaseRel, stage, E, NB);
            p2<<<NB, 512, 0, stream>>>(stage, cptr, colsrc, row_ptr, n);

            // 16 lanes per node, 4 nodes per wave
            const int gblocks = ((size_t)n * 16 + 255) / 256;
            k_gather8f<<<gblocks, 256, 0, stream>>>(row_ptr, colsrc, as1, ad1, h1,
                                                    b1, W2, a2s, a2d, g, as2, ad2, n);
            k_gather16<<<gblocks, 256, 0, stream>>>(row_ptr, colsrc, as2, ad2, g, b2, out, n);
            return;
        }
    }

    // ---- fallback: pure atomic path (fp32) ----
    {
        float* ws     = (float*)d_ws;
        float* denom1 = ws;
        float* acc1   = ws + (size_t)n;
        float* denom2 = ws + (size_t)9 * n;
        float* acc2   = ws + (size_t)10 * n;
        float* h1     = ws + (size_t)26 * n;
        float* as1    = ws + (size_t)34 * n;
        float* ad1    = ws + (size_t)35 * n;
        float* g      = ws + (size_t)36 * n;
        float* as2    = ws + (size_t)52 * n;
        float* ad2    = ws + (size_t)53 * n;

        hipMemsetAsync(ws, 0, (size_t)26 * n * sizeof(float), stream);
        k1_nodeF<<<(n + 7) / 8, 256, 0, stream>>>(x, W1, a1s, a1d, h1, as1, ad1, n);
        k_edge<8><<<(E + 255) / 256, 256, 0, stream>>>(src, dst, as1, ad1, h1, denom1, acc1, E);
        k3_node<<<(n + 255) / 256, 256, 0, stream>>>(denom1, acc1, b1, W2, a2s, a2d, g, as2, ad2, n);
        k_edge<16><<<(E + 255) / 256, 256, 0, stream>>>(src, dst, as2, ad2, g, denom2, acc2, E);
        k5_final<<<(n + 255) / 256, 256, 0, stream>>>(denom2, acc2, b2, out, n);
    }
}

// Round 14
// 272.167 us; speedup vs baseline: 4.5767x; 1.0876x over previous
//
#include <hip/hip_runtime.h>
#include <hip/hip_fp16.h>
#include <math.h>
#include <stdint.h>

#define NEG 0.2f
#define CSHIFT 9
#define BUCKN (1 << CSHIFT)     // 512 nodes per bucket
#define MAXNB 256               // NB <= 256 for n <= 131072 (CSHIFT=9)
#define CHUNK 4096

// ============================ node transform (fp16 h1 out) ============================

__global__ __launch_bounds__(256) void k1_node(const float* __restrict__ x,
    const float* __restrict__ W1, const float* __restrict__ a1s, const float* __restrict__ a1d,
    __half* __restrict__ h1, float* __restrict__ as1, float* __restrict__ ad1, int n)
{
    __shared__ float wt[8 * 128];
    __shared__ float av[16];
    for (int i = threadIdx.x; i < 1024; i += 256) {
        int r = i >> 3, k = i & 7;
        wt[k * 128 + r] = W1[i];
    }
    if (threadIdx.x < 8)        av[threadIdx.x] = a1s[threadIdx.x];
    else if (threadIdx.x < 16)  av[threadIdx.x] = a1d[threadIdx.x - 8];
    __syncthreads();

    int lane = threadIdx.x & 31;
    int node = blockIdx.x * 8 + (threadIdx.x >> 5);
    if (node >= n) return;

    float4 xv = ((const float4*)(x + (size_t)node * 128))[lane];
    float p[8];
#pragma unroll
    for (int k = 0; k < 8; ++k) {
        float4 wv = ((const float4*)(wt + k * 128))[lane];
        p[k] = xv.x * wv.x + xv.y * wv.y + xv.z * wv.z + xv.w * wv.w;
    }
#pragma unroll
    for (int off = 16; off; off >>= 1)
#pragma unroll
        for (int k = 0; k < 8; ++k) p[k] += __shfl_down(p[k], off, 32);

    if (lane == 0) {
        float s = 0.f, d = 0.f;
        union { float4 f; __half2 h[4]; } u;
#pragma unroll
        for (int k = 0; k < 8; ++k) {
            s += p[k] * av[k];
            d += p[k] * av[8 + k];
        }
#pragma unroll
        for (int q = 0; q < 4; ++q) u.h[q] = __floats2half2_rn(p[2 * q], p[2 * q + 1]);
        ((float4*)h1)[node] = u.f;   // 16B fp16 row
        as1[node] = s;
        ad1[node] = d;
    }
}

// ============================ bucket-sort CSR build (all-parallel, atomic-free) ============================

__global__ __launch_bounds__(256) void p1a(const int* __restrict__ dst, int* __restrict__ gmat,
                                           int E, int NB)
{
    __shared__ int h[MAXNB];
    for (int i = threadIdx.x; i < NB; i += 256) h[i] = 0;
    __syncthreads();
    int base = blockIdx.x * CHUNK;
    int end = base + CHUNK; if (end > E) end = E;
    for (int i = base + threadIdx.x; i < end; i += 256)
        atomicAdd(&h[dst[i] >> CSHIFT], 1);
    __syncthreads();
    int* row = gmat + (size_t)blockIdx.x * NB;
    for (int i = threadIdx.x; i < NB; i += 256) row[i] = h[i];
}

__global__ __launch_bounds__(256) void pcol(const int* __restrict__ gmat, int* __restrict__ pbaseRel,
    int* __restrict__ total, int NBLK, int NB)
{
    __shared__ int wsum[4];
    int b = blockIdx.x;
    int tid = threadIdx.x;
    int chunk = (NBLK + 255) >> 8;
    int k0 = tid * chunk;
    int s = 0;
    for (int j = 0; j < chunk; ++j) {
        int k = k0 + j;
        if (k < NBLK) s += gmat[(size_t)k * NB + b];
    }
    int lane = tid & 63, w = tid >> 6;
    int sc = s;
#pragma unroll
    for (int off = 1; off < 64; off <<= 1) {
        int t = __shfl_up(sc, off, 64);
        if (lane >= off) sc += t;
    }
    if (lane == 63) wsum[w] = sc;
    __syncthreads();
    if (tid == 0) { int a = 0; for (int i = 0; i < 4; ++i) { int t = wsum[i]; wsum[i] = a; a += t; } }
    __syncthreads();
    int run = sc - s + wsum[w];
    for (int j = 0; j < chunk; ++j) {
        int k = k0 + j;
        if (k < NBLK) {
            int gv = gmat[(size_t)k * NB + b];
            pbaseRel[(size_t)k * NB + b] = run;
            run += gv;
        }
    }
    if (tid == 255) total[b] = run;
}

__global__ __launch_bounds__(512) void ptot(const int* __restrict__ total, int* __restrict__ cptr,
                                            int* __restrict__ row_ptr, int NB, int n, int E)
{
    __shared__ int wsum[8];
    int b = threadIdx.x;
    int v = b < NB ? total[b] : 0;
    int lane = b & 63, w = b >> 6;
    int s = v;
#pragma unroll
    for (int off = 1; off < 64; off <<= 1) {
        int t = __shfl_up(s, off, 64);
        if (lane >= off) s += t;
    }
    if (lane == 63) wsum[w] = s;
    __syncthreads();
    if (b == 0) { int a = 0; for (int i = 0; i < 8; ++i) { int t = wsum[i]; wsum[i] = a; a += t; } }
    __syncthreads();
    int excl = s - v + wsum[w];
    if (b < NB) cptr[b] = excl;
    if (b == 0) { cptr[NB] = E; row_ptr[n] = E; }
}

// pass 1b with LDS write-combining: locally sort chunk by bucket, flush contiguous runs.
__global__ __launch_bounds__(256) void p1bW(const int* __restrict__ src, const int* __restrict__ dst,
    const int* __restrict__ cptr, const int* __restrict__ pbaseRel, unsigned* __restrict__ stage,
    int E, int NB)
{
    __shared__ int hh[MAXNB], lbase[MAXNB], bbase[MAXNB], ccur[MAXNB];
    __shared__ unsigned bufp[CHUNK];
    __shared__ unsigned short bufb[CHUNK];
    __shared__ int wsum[4];
    int tid = threadIdx.x;
    if (tid < NB) { hh[tid] = 0; ccur[tid] = 0; }
    __syncthreads();

    int base = blockIdx.x * CHUNK;
    int end = base + CHUNK; if (end > E) end = E;
    int cnt = end - base;

    // 1. local histogram
    for (int i = base + tid; i < end; i += 256)
        atomicAdd(&hh[dst[i] >> CSHIFT], 1);
    __syncthreads();

    // 2. 256-thread exclusive scan over NB (<=256) buckets
    int v = (tid < NB) ? hh[tid] : 0;
    int lane = tid & 63, w = tid >> 6;
    int sc = v;
#pragma unroll
    for (int off = 1; off < 64; off <<= 1) {
        int t = __shfl_up(sc, off, 64);
        if (lane >= off) sc += t;
    }
    if (lane == 63) wsum[w] = sc;
    __syncthreads();
    if (tid == 0) { int a = 0; for (int i = 0; i < 4; ++i) { int t = wsum[i]; wsum[i] = a; a += t; } }
    __syncthreads();
    if (tid < NB) {
        lbase[tid] = sc - v + wsum[w];
        bbase[tid] = cptr[tid] + pbaseRel[(size_t)blockIdx.x * NB + tid];
    }
    __syncthreads();

    // 3. LDS scatter (random LDS, cheap)
    for (int i = base + tid; i < end; i += 256) {
        int d = dst[i];
        int b = d >> CSHIFT;
        int off = atomicAdd(&ccur[b], 1);
        int pos = lbase[b] + off;
        bufp[pos] = ((unsigned)(d & (BUCKN - 1)) << 17) | (unsigned)src[i];
        bufb[pos] = (unsigned short)b;
    }
    __syncthreads();

    // 4. flush: consecutive local positions within a bucket -> consecutive global
    for (int i = tid; i < cnt; i += 256) {
        int b = bufb[i];
        stage[bbase[b] + (i - lbase[b])] = bufp[i];
    }
}

// pass 2: per-bucket fine counting-sort (512-node buckets) -> colsrc + row_ptr
__global__ __launch_bounds__(512) void p2(const unsigned* __restrict__ stage,
    const int* __restrict__ cptr, int* __restrict__ colsrc, int* __restrict__ row_ptr, int n)
{
    int b = blockIdx.x;
    int nbase = b << CSHIFT;
    int NN = n - nbase; if (NN > BUCKN) NN = BUCKN;
    __shared__ int h[BUCKN], bps[BUCKN], cc[BUCKN];
    __shared__ int wsum[8];
    int tid = threadIdx.x;
    h[tid] = 0; cc[tid] = 0;
    __syncthreads();
    int s0 = cptr[b], s1 = cptr[b + 1];
    for (int i = s0 + tid; i < s1; i += 512)
        atomicAdd(&h[stage[i] >> 17], 1);
    __syncthreads();
    int v = h[tid];
    int lane = tid & 63, w = tid >> 6;
    int sc = v;
#pragma unroll
    for (int off = 1; off < 64; off <<= 1) {
        int t = __shfl_up(sc, off, 64);
        if (lane >= off) sc += t;
    }
    if (lane == 63) wsum[w] = sc;
    __syncthreads();
    if (tid == 0) { int a = 0; for (int i = 0; i < 8; ++i) { int t = wsum[i]; wsum[i] = a; a += t; } }
    __syncthreads();
    int excl = sc - v + wsum[w];
    bps[tid] = s0 + excl;
    if (tid < NN) row_ptr[nbase + tid] = s0 + excl;
    __syncthreads();
    for (int i = s0 + tid; i < s1; i += 512) {
        unsigned p = stage[i];
        int f = p >> 17;
        int off = atomicAdd(&cc[f], 1);
        colsrc[bps[f] + off] = (int)(p & 0x1FFFFu);
    }
}

// ============================ gathers (fp16 features, 16 lanes/node, 4 nodes/wave) ============================

__global__ __launch_bounds__(256) void k_gather8f(const int* __restrict__ row_ptr,
    const int* __restrict__ colsrc, const float* __restrict__ as, const float* __restrict__ ad,
    const __half* __restrict__ feat, const float* __restrict__ b1,
    const float* __restrict__ W2, const float* __restrict__ a2s, const float* __restrict__ a2d,
    __half* __restrict__ g, float* __restrict__ as2, float* __restrict__ ad2, int n)
{
    __shared__ float w2s[128], a2sv[16], a2dv[16], b1v[8];
    if (threadIdx.x < 128) w2s[threadIdx.x] = W2[threadIdx.x];
    else if (threadIdx.x < 144) a2sv[threadIdx.x - 128] = a2s[threadIdx.x - 128];
    else if (threadIdx.x < 160) a2dv[threadIdx.x - 144] = a2d[threadIdx.x - 144];
    else if (threadIdx.x < 168) b1v[threadIdx.x - 160] = b1[threadIdx.x - 160];
    __syncthreads();

    int wid  = (blockIdx.x * 256 + threadIdx.x) >> 6;
    int lane = threadIdx.x & 63;
    int l16  = lane & 15;
    int node = wid * 4 + (lane >> 4);
    bool active = node < n;

    int start = 0, end = 0;
    float adn = 0.f;
    if (active) { start = row_ptr[node]; end = row_ptr[node + 1]; adn = ad[node]; }

    float wsum = 0.f, acc[8];
#pragma unroll
    for (int k = 0; k < 8; ++k) acc[k] = 0.f;

    for (int i = start + l16; i < end; i += 16) {
        int s = colsrc[i];
        float t = as[s] + adn;
        float w = __expf(t > 0.f ? t : NEG * t);  // max-shift skipped: |t| small, exact ratio
        wsum += w;
        union { float4 fv; __half2 h[4]; } u;
        u.fv = ((const float4*)feat)[s];          // 16B fp16 row
#pragma unroll
        for (int q = 0; q < 4; ++q) {
            float2 hv = __half22float2(u.h[q]);
            acc[2 * q + 0] += w * hv.x;
            acc[2 * q + 1] += w * hv.y;
        }
    }
#pragma unroll
    for (int off = 8; off; off >>= 1) {
        wsum += __shfl_xor(wsum, off, 64);
#pragma unroll
        for (int k = 0; k < 8; ++k) acc[k] += __shfl_xor(acc[k], off, 64);
    }
    if (!active) return;

    float inv = wsum > 0.f ? 1.f / wsum : 0.f;
    float h[8];
#pragma unroll
    for (int k = 0; k < 8; ++k) {
        float v = acc[k] * inv + b1v[k];
        h[k] = v > 0.f ? v : 0.f;
    }
    float gv = 0.f;
#pragma unroll
    for (int k = 0; k < 8; ++k) gv += h[k] * w2s[k * 16 + l16];
    float po = __shfl_xor(gv, 1, 64);
    if ((l16 & 1) == 0)
        ((__half2*)(g + (size_t)node * 16))[l16 >> 1] = __floats2half2_rn(gv, po);
    float ps = gv * a2sv[l16];
    float pd = gv * a2dv[l16];
#pragma unroll
    for (int off = 8; off; off >>= 1) {
        ps += __shfl_xor(ps, off, 64);
        pd += __shfl_xor(pd, off, 64);
    }
    if (l16 == 0) { as2[node] = ps; ad2[node] = pd; }
}

__global__ __launch_bounds__(256) void k_gather16(const int* __restrict__ row_ptr,
    const int* __restrict__ colsrc, const float* __restrict__ as, const float* __restrict__ ad,
    const __half* __restrict__ feat, const float* __restrict__ bias, float* __restrict__ outp, int n)
{
    __shared__ float bv[16];
    if (threadIdx.x < 16) bv[threadIdx.x] = bias[threadIdx.x];
    __syncthreads();

    int wid  = (blockIdx.x * 256 + threadIdx.x) >> 6;
    int lane = threadIdx.x & 63;
    int l16  = lane & 15;
    int node = wid * 4 + (lane >> 4);
    bool active = node < n;

    int start = 0, end = 0;
    float adn = 0.f;
    if (active) { start = row_ptr[node]; end = row_ptr[node + 1]; adn = ad[node]; }

    float wsum = 0.f, acc[16];
#pragma unroll
    for (int k = 0; k < 16; ++k) acc[k] = 0.f;

    for (int i = start + l16; i < end; i += 16) {
        int s = colsrc[i];
        float t = as[s] + adn;
        float w = __expf(t > 0.f ? t : NEG * t);
        wsum += w;
        union { float4 fv[2]; __half2 h[8]; } u;
        const float4* gs = (const float4*)(feat + (size_t)s * 16);  // 32B fp16 row
        u.fv[0] = gs[0];
        u.fv[1] = gs[1];
#pragma unroll
        for (int q = 0; q < 8; ++q) {
            float2 gv = __half22float2(u.h[q]);
            acc[2 * q + 0] += w * gv.x;
            acc[2 * q + 1] += w * gv.y;
        }
    }
#pragma unroll
    for (int off = 8; off; off >>= 1) {
        wsum += __shfl_xor(wsum, off, 64);
#pragma unroll
        for (int k = 0; k < 16; ++k) acc[k] += __shfl_xor(acc[k], off, 64);
    }
    if (!active) return;

    float inv = wsum > 0.f ? 1.f / wsum : 0.f;
    float o[16], m = -1e30f;
#pragma unroll
    for (int c = 0; c < 16; ++c) {
        o[c] = acc[c] * inv + bv[c];
        m = fmaxf(m, o[c]);
    }
    float se = 0.f;
#pragma unroll
    for (int c = 0; c < 16; ++c) se += __expf(o[c] - m);
    float l = m + __logf(se);
    outp[(size_t)node * 16 + l16] = o[l16] - l;
}

// ============================ fallback: pure atomic path (fp32) ============================

__global__ __launch_bounds__(256) void k1_nodeF(const float* __restrict__ x,
    const float* __restrict__ W1, const float* __restrict__ a1s, const float* __restrict__ a1d,
    float* __restrict__ h1, float* __restrict__ as1, float* __restrict__ ad1, int n)
{
    __shared__ float wt[8 * 128];
    __shared__ float av[16];
    for (int i = threadIdx.x; i < 1024; i += 256) {
        int r = i >> 3, k = i & 7;
        wt[k * 128 + r] = W1[i];
    }
    if (threadIdx.x < 8)        av[threadIdx.x] = a1s[threadIdx.x];
    else if (threadIdx.x < 16)  av[threadIdx.x] = a1d[threadIdx.x - 8];
    __syncthreads();

    int lane = threadIdx.x & 31;
    int node = blockIdx.x * 8 + (threadIdx.x >> 5);
    if (node >= n) return;

    float4 xv = ((const float4*)(x + (size_t)node * 128))[lane];
    float p[8];
#pragma unroll
    for (int k = 0; k < 8; ++k) {
        float4 wv = ((const float4*)(wt + k * 128))[lane];
        p[k] = xv.x * wv.x + xv.y * wv.y + xv.z * wv.z + xv.w * wv.w;
    }
#pragma unroll
    for (int off = 16; off; off >>= 1)
#pragma unroll
        for (int k = 0; k < 8; ++k) p[k] += __shfl_down(p[k], off, 32);

    if (lane == 0) {
        float s = 0.f, d = 0.f;
#pragma unroll
        for (int k = 0; k < 8; ++k) {
            h1[(size_t)node * 8 + k] = p[k];
            s += p[k] * av[k];
            d += p[k] * av[8 + k];
        }
        as1[node] = s;
        ad1[node] = d;
    }
}

template <int F>
__global__ __launch_bounds__(256) void k_edge(const int* __restrict__ src, const int* __restrict__ dst,
    const float* __restrict__ as, const float* __restrict__ ad, const float* __restrict__ feat,
    float* __restrict__ denom, float* __restrict__ acc, int E)
{
    int e = blockIdx.x * 256 + threadIdx.x;
    if (e >= E) return;
    int s = src[e], d = dst[e];
    float t = as[s] + ad[d];
    float w = __expf(t > 0.f ? t : NEG * t);
    atomicAdd(denom + d, w);
    const float* fs = feat + (size_t)s * F;
    float* ac = acc + (size_t)d * F;
#pragma unroll
    for (int k = 0; k < F; ++k) atomicAdd(ac + k, w * fs[k]);
}

__global__ __launch_bounds__(256) void k3_node(const float* __restrict__ denom1,
    const float* __restrict__ acc1, const float* __restrict__ b1,
    const float* __restrict__ W2, const float* __restrict__ a2s, const float* __restrict__ a2d,
    float* __restrict__ g, float* __restrict__ as2, float* __restrict__ ad2, int n)
{
    __shared__ float w2[128];
    __shared__ float aa[32];
    __shared__ float bb[8];
    if (threadIdx.x < 128) w2[threadIdx.x] = W2[threadIdx.x];
    if (threadIdx.x >= 128 && threadIdx.x < 144) aa[threadIdx.x - 128] = a2s[threadIdx.x - 128];
    if (threadIdx.x >= 144 && threadIdx.x < 160) aa[16 + threadIdx.x - 144] = a2d[threadIdx.x - 144];
    if (threadIdx.x >= 160 && threadIdx.x < 168) bb[threadIdx.x - 160] = b1[threadIdx.x - 160];
    __syncthreads();

    int node = blockIdx.x * 256 + threadIdx.x;
    if (node >= n) return;
    float dn = denom1[node];
    float inv = dn > 0.f ? 1.f / dn : 0.f;
    float h[8];
#pragma unroll
    for (int k = 0; k < 8; ++k) {
        float v = acc1[(size_t)node * 8 + k] * inv + bb[k];
        h[k] = v > 0.f ? v : 0.f;
    }
    float s = 0.f, dd = 0.f;
#pragma unroll
    for (int c = 0; c < 16; ++c) {
        float gv = 0.f;
#pragma unroll
        for (int k = 0; k < 8; ++k) gv += h[k] * w2[k * 16 + c];
        g[(size_t)node * 16 + c] = gv;
        s += gv * aa[c];
        dd += gv * aa[16 + c];
    }
    as2[node] = s;
    ad2[node] = dd;
}

__global__ __launch_bounds__(256) void k5_final(const float* __restrict__ denom2,
    const float* __restrict__ acc2, const float* __restrict__ b2, float* __restrict__ out, int n)
{
    __shared__ float bb[16];
    if (threadIdx.x < 16) bb[threadIdx.x] = b2[threadIdx.x];
    __syncthreads();

    int node = blockIdx.x * 256 + threadIdx.x;
    if (node >= n) return;
    float dn = denom2[node];
    float inv = dn > 0.f ? 1.f / dn : 0.f;
    float o[16];
    float m = -1e30f;
#pragma unroll
    for (int c = 0; c < 16; ++c) {
        o[c] = acc2[(size_t)node * 16 + c] * inv + bb[c];
        m = fmaxf(m, o[c]);
    }
    float se = 0.f;
#pragma unroll
    for (int c = 0; c < 16; ++c) {
        o[c] -= m;
        se += __expf(o[c]);
    }
    float l = __logf(se);
#pragma unroll
    for (int c = 0; c < 16; ++c) out[(size_t)node * 16 + c] = o[c] - l;
}

// ============================ launch ============================

static inline char* align256(char* p) {
    return (char*)(((uintptr_t)p + 255) & ~(uintptr_t)255);
}

extern "C" void kernel_launch(void* const* d_in, const int* in_sizes, int n_in,
                              void* d_out, int out_size, void* d_ws, size_t ws_size,
                              hipStream_t stream)
{
    const float* x    = (const float*)d_in[0];
    const int*   eidx = (const int*)d_in[1];
    const float* W1   = (const float*)d_in[2];
    const float* a1s  = (const float*)d_in[3];
    const float* a1d  = (const float*)d_in[4];
    const float* b1   = (const float*)d_in[5];
    const float* W2   = (const float*)d_in[6];
    const float* a2s  = (const float*)d_in[7];
    const float* a2d  = (const float*)d_in[8];
    const float* b2   = (const float*)d_in[9];
    float* out = (float*)d_out;

    const int n = in_sizes[0] / 128;
    const int E = in_sizes[1] / 2;
    const int* src = eidx;
    const int* dst = eidx + E;
    const int NB = (n + BUCKN - 1) >> CSHIFT;
    const int NBLK = (E + CHUNK - 1) / CHUNK;

    // ---- tier-0: bucket-sort CSR (gmat/pbaseRel aliased into colsrc) + fp16 gathers ----
    {
        char* p = (char*)d_ws;
        char* p0 = p;
        unsigned* stage = (unsigned*)p;  p = align256(p + (size_t)E * 4);
        int* colsrc  = (int*)p;          p = align256(p + (size_t)E * 4);
        int* total   = (int*)p;          p = align256(p + (size_t)NB * 4);
        int* cptr    = (int*)p;          p = align256(p + (size_t)(NB + 1) * 4);
        int* row_ptr = (int*)p;          p = align256(p + (size_t)(n + 1) * 4);
        __half* h1   = (__half*)p;       p = align256(p + (size_t)8 * n * 2);
        __half* g    = (__half*)p;       p = align256(p + (size_t)16 * n * 2);
        float* as1   = (float*)p;        p = align256(p + (size_t)n * 4);
        float* ad1   = (float*)p;        p = align256(p + (size_t)n * 4);
        float* as2   = (float*)p;        p = align256(p + (size_t)n * 4);
        float* ad2   = (float*)p;        p = align256(p + (size_t)n * 4);
        size_t needed = (size_t)(p - p0);

        int* gmat     = colsrc;                       // alias (dead before p2)
        int* pbaseRel = (int*)align256((char*)(colsrc + (size_t)NBLK * NB));

        bool alias_ok = ((size_t)2 * NBLK * NB + 64) <= (size_t)E;

        if (n <= 131072 && NB <= MAXNB && alias_ok && ws_size >= needed) {
            k1_node<<<(n + 7) / 8, 256, 0, stream>>>(x, W1, a1s, a1d, h1, as1, ad1, n);

            p1a<<<NBLK, 256, 0, stream>>>(dst, gmat, E, NB);
            pcol<<<NB, 256, 0, stream>>>(gmat, pbaseRel, total, NBLK, NB);
            ptot<<<1, 512, 0, stream>>>(total, cptr, row_ptr, NB, n, E);
            p1bW<<<NBLK, 256, 0, stream>>>(src, dst, cptr, pbaseRel, stage, E, NB);
            p2<<<NB, 512, 0, stream>>>(stage, cptr, colsrc, row_ptr, n);

            // 16 lanes per node, 4 nodes per wave
            const int gblocks = ((size_t)n * 16 + 255) / 256;
            k_gather8f<<<gblocks, 256, 0, stream>>>(row_ptr, colsrc, as1, ad1, h1,
                                                    b1, W2, a2s, a2d, g, as2, ad2, n);
            k_gather16<<<gblocks, 256, 0, stream>>>(row_ptr, colsrc, as2, ad2, g, b2, out, n);
            return;
        }
    }

    // ---- fallback: pure atomic path (fp32) ----
    {
        float* ws     = (float*)d_ws;
        float* denom1 = ws;
        float* acc1   = ws + (size_t)n;
        float* denom2 = ws + (size_t)9 * n;
        float* acc2   = ws + (size_t)10 * n;
        float* h1     = ws + (size_t)26 * n;
        float* as1    = ws + (size_t)34 * n;
        float* ad1    = ws + (size_t)35 * n;
        float* g      = ws + (size_t)36 * n;
        float* as2    = ws + (size_t)52 * n;
        float* ad2    = ws + (size_t)53 * n;

        hipMemsetAsync(ws, 0, (size_t)26 * n * sizeof(float), stream);
        k1_nodeF<<<(n + 7) / 8, 256, 0, stream>>>(x, W1, a1s, a1d, h1, as1, ad1, n);
        k_edge<8><<<(E + 255) / 256, 256, 0, stream>>>(src, dst, as1, ad1, h1, denom1, acc1, E);
        k3_node<<<(n + 255) / 256, 256, 0, stream>>>(denom1, acc1, b1, W2, a2s, a2d, g, as2, ad2, n);
        k_edge<16><<<(E + 255) / 256, 256, 0, stream>>>(src, dst, as2, ad2, g, denom2, acc2, E);
        k5_final<<<(n + 255) / 256, 256, 0, stream>>>(denom2, acc2, b2, out, n);
    }
}

// Round 15
// 260.021 us; speedup vs baseline: 4.7905x; 1.0467x over previous
//
#include <hip/hip_runtime.h>
#include <hip/hip_fp16.h>
#include <math.h>
#include <stdint.h>

#define NEG 0.2f
#define CSHIFT 9
#define BUCKN (1 << CSHIFT)     // 512 nodes per bucket
#define MAXNB 256               // NB <= 256 for n <= 131072 (CSHIFT=9)
#define CHUNK 4096

// ============================ node transform (fp16 h1 out) ============================

__global__ __launch_bounds__(256) void k1_node(const float* __restrict__ x,
    const float* __restrict__ W1, const float* __restrict__ a1s, const float* __restrict__ a1d,
    __half* __restrict__ h1, float* __restrict__ as1, float* __restrict__ ad1, int n)
{
    __shared__ float wt[8 * 128];
    __shared__ float av[16];
    for (int i = threadIdx.x; i < 1024; i += 256) {
        int r = i >> 3, k = i & 7;
        wt[k * 128 + r] = W1[i];
    }
    if (threadIdx.x < 8)        av[threadIdx.x] = a1s[threadIdx.x];
    else if (threadIdx.x < 16)  av[threadIdx.x] = a1d[threadIdx.x - 8];
    __syncthreads();

    int lane = threadIdx.x & 31;
    int node = blockIdx.x * 8 + (threadIdx.x >> 5);
    if (node >= n) return;

    float4 xv = ((const float4*)(x + (size_t)node * 128))[lane];
    float p[8];
#pragma unroll
    for (int k = 0; k < 8; ++k) {
        float4 wv = ((const float4*)(wt + k * 128))[lane];
        p[k] = xv.x * wv.x + xv.y * wv.y + xv.z * wv.z + xv.w * wv.w;
    }
#pragma unroll
    for (int off = 16; off; off >>= 1)
#pragma unroll
        for (int k = 0; k < 8; ++k) p[k] += __shfl_down(p[k], off, 32);

    if (lane == 0) {
        float s = 0.f, d = 0.f;
        union { float4 f; __half2 h[4]; } u;
#pragma unroll
        for (int k = 0; k < 8; ++k) {
            s += p[k] * av[k];
            d += p[k] * av[8 + k];
        }
#pragma unroll
        for (int q = 0; q < 4; ++q) u.h[q] = __floats2half2_rn(p[2 * q], p[2 * q + 1]);
        ((float4*)h1)[node] = u.f;   // 16B fp16 row
        as1[node] = s;
        ad1[node] = d;
    }
}

// ============================ bucket-sort CSR build (all-parallel, atomic-free) ============================

__global__ __launch_bounds__(256) void p1a(const int* __restrict__ dst, int* __restrict__ gmat,
                                           int E, int NB)
{
    __shared__ int h[MAXNB];
    for (int i = threadIdx.x; i < NB; i += 256) h[i] = 0;
    __syncthreads();
    int base = blockIdx.x * CHUNK;
    int end = base + CHUNK; if (end > E) end = E;
    for (int i = base + threadIdx.x; i < end; i += 256)
        atomicAdd(&h[dst[i] >> CSHIFT], 1);
    __syncthreads();
    int* row = gmat + (size_t)blockIdx.x * NB;
    for (int i = threadIdx.x; i < NB; i += 256) row[i] = h[i];
}

__global__ __launch_bounds__(256) void pcol(const int* __restrict__ gmat, int* __restrict__ pbaseRel,
    int* __restrict__ total, int NBLK, int NB)
{
    __shared__ int wsum[4];
    int b = blockIdx.x;
    int tid = threadIdx.x;
    int chunk = (NBLK + 255) >> 8;
    int k0 = tid * chunk;
    int s = 0;
    for (int j = 0; j < chunk; ++j) {
        int k = k0 + j;
        if (k < NBLK) s += gmat[(size_t)k * NB + b];
    }
    int lane = tid & 63, w = tid >> 6;
    int sc = s;
#pragma unroll
    for (int off = 1; off < 64; off <<= 1) {
        int t = __shfl_up(sc, off, 64);
        if (lane >= off) sc += t;
    }
    if (lane == 63) wsum[w] = sc;
    __syncthreads();
    if (tid == 0) { int a = 0; for (int i = 0; i < 4; ++i) { int t = wsum[i]; wsum[i] = a; a += t; } }
    __syncthreads();
    int run = sc - s + wsum[w];
    for (int j = 0; j < chunk; ++j) {
        int k = k0 + j;
        if (k < NBLK) {
            int gv = gmat[(size_t)k * NB + b];
            pbaseRel[(size_t)k * NB + b] = run;
            run += gv;
        }
    }
    if (tid == 255) total[b] = run;
}

__global__ __launch_bounds__(512) void ptot(const int* __restrict__ total, int* __restrict__ cptr,
                                            int* __restrict__ row_ptr, int NB, int n, int E)
{
    __shared__ int wsum[8];
    int b = threadIdx.x;
    int v = b < NB ? total[b] : 0;
    int lane = b & 63, w = b >> 6;
    int s = v;
#pragma unroll
    for (int off = 1; off < 64; off <<= 1) {
        int t = __shfl_up(s, off, 64);
        if (lane >= off) s += t;
    }
    if (lane == 63) wsum[w] = s;
    __syncthreads();
    if (b == 0) { int a = 0; for (int i = 0; i < 8; ++i) { int t = wsum[i]; wsum[i] = a; a += t; } }
    __syncthreads();
    int excl = s - v + wsum[w];
    if (b < NB) cptr[b] = excl;
    if (b == 0) { cptr[NB] = E; row_ptr[n] = E; }
}

// pass 1b with LDS write-combining: locally sort chunk by bucket, flush contiguous runs.
__global__ __launch_bounds__(256) void p1bW(const int* __restrict__ src, const int* __restrict__ dst,
    const int* __restrict__ cptr, const int* __restrict__ pbaseRel, unsigned* __restrict__ stage,
    int E, int NB)
{
    __shared__ int hh[MAXNB], lbase[MAXNB], bbase[MAXNB], ccur[MAXNB];
    __shared__ unsigned bufp[CHUNK];
    __shared__ unsigned short bufb[CHUNK];
    __shared__ int wsum[4];
    int tid = threadIdx.x;
    if (tid < NB) { hh[tid] = 0; ccur[tid] = 0; }
    __syncthreads();

    int base = blockIdx.x * CHUNK;
    int end = base + CHUNK; if (end > E) end = E;
    int cnt = end - base;

    for (int i = base + tid; i < end; i += 256)
        atomicAdd(&hh[dst[i] >> CSHIFT], 1);
    __syncthreads();

    int v = (tid < NB) ? hh[tid] : 0;
    int lane = tid & 63, w = tid >> 6;
    int sc = v;
#pragma unroll
    for (int off = 1; off < 64; off <<= 1) {
        int t = __shfl_up(sc, off, 64);
        if (lane >= off) sc += t;
    }
    if (lane == 63) wsum[w] = sc;
    __syncthreads();
    if (tid == 0) { int a = 0; for (int i = 0; i < 4; ++i) { int t = wsum[i]; wsum[i] = a; a += t; } }
    __syncthreads();
    if (tid < NB) {
        lbase[tid] = sc - v + wsum[w];
        bbase[tid] = cptr[tid] + pbaseRel[(size_t)blockIdx.x * NB + tid];
    }
    __syncthreads();

    for (int i = base + tid; i < end; i += 256) {
        int d = dst[i];
        int b = d >> CSHIFT;
        int off = atomicAdd(&ccur[b], 1);
        int pos = lbase[b] + off;
        bufp[pos] = ((unsigned)(d & (BUCKN - 1)) << 17) | (unsigned)src[i];
        bufb[pos] = (unsigned short)b;
    }
    __syncthreads();

    for (int i = tid; i < cnt; i += 256) {
        int b = bufb[i];
        stage[bbase[b] + (i - lbase[b])] = bufp[i];
    }
}

// pass 2: per-bucket fine counting-sort (512-node buckets) -> colsrc + row_ptr
__global__ __launch_bounds__(512) void p2(const unsigned* __restrict__ stage,
    const int* __restrict__ cptr, int* __restrict__ colsrc, int* __restrict__ row_ptr, int n)
{
    int b = blockIdx.x;
    int nbase = b << CSHIFT;
    int NN = n - nbase; if (NN > BUCKN) NN = BUCKN;
    __shared__ int h[BUCKN], bps[BUCKN], cc[BUCKN];
    __shared__ int wsum[8];
    int tid = threadIdx.x;
    h[tid] = 0; cc[tid] = 0;
    __syncthreads();
    int s0 = cptr[b], s1 = cptr[b + 1];
    for (int i = s0 + tid; i < s1; i += 512)
        atomicAdd(&h[stage[i] >> 17], 1);
    __syncthreads();
    int v = h[tid];
    int lane = tid & 63, w = tid >> 6;
    int sc = v;
#pragma unroll
    for (int off = 1; off < 64; off <<= 1) {
        int t = __shfl_up(sc, off, 64);
        if (lane >= off) sc += t;
    }
    if (lane == 63) wsum[w] = sc;
    __syncthreads();
    if (tid == 0) { int a = 0; for (int i = 0; i < 8; ++i) { int t = wsum[i]; wsum[i] = a; a += t; } }
    __syncthreads();
    int excl = sc - v + wsum[w];
    bps[tid] = s0 + excl;
    if (tid < NN) row_ptr[nbase + tid] = s0 + excl;
    __syncthreads();
    for (int i = s0 + tid; i < s1; i += 512) {
        unsigned p = stage[i];
        int f = p >> 17;
        int off = atomicAdd(&cc[f], 1);
        colsrc[bps[f] + off] = (int)(p & 0x1FFFFu);
    }
}

// ============================ gathers (fp16 features, 16 lanes/node, 4 nodes/wave) ============================

// Layer 1 gather -> h' = relu(acc/denom + b1), stored fp16.
// as2/ad2 computed via precomputed W2@a2s / W2@a2d (aggregation commutes with W2).
__global__ __launch_bounds__(256) void k_gather8f(const int* __restrict__ row_ptr,
    const int* __restrict__ colsrc, const float* __restrict__ as, const float* __restrict__ ad,
    const __half* __restrict__ feat, const float* __restrict__ b1,
    const float* __restrict__ W2, const float* __restrict__ a2s, const float* __restrict__ a2d,
    __half* __restrict__ h1p, float* __restrict__ as2, float* __restrict__ ad2, int n)
{
    __shared__ float w2as[8], w2ad[8], b1v[8];
    if (threadIdx.x < 8) {
        float s = 0.f, d = 0.f;
#pragma unroll
        for (int c = 0; c < 16; ++c) {
            float wv = W2[threadIdx.x * 16 + c];
            s += wv * a2s[c];
            d += wv * a2d[c];
        }
        w2as[threadIdx.x] = s;
        w2ad[threadIdx.x] = d;
        b1v[threadIdx.x] = b1[threadIdx.x];
    }
    __syncthreads();

    int wid  = (blockIdx.x * 256 + threadIdx.x) >> 6;
    int lane = threadIdx.x & 63;
    int l16  = lane & 15;
    int node = wid * 4 + (lane >> 4);
    bool active = node < n;

    int start = 0, end = 0;
    float adn = 0.f;
    if (active) { start = row_ptr[node]; end = row_ptr[node + 1]; adn = ad[node]; }

    float wsum = 0.f, acc[8];
#pragma unroll
    for (int k = 0; k < 8; ++k) acc[k] = 0.f;

    for (int i = start + l16; i < end; i += 16) {
        int s = colsrc[i];
        float t = as[s] + adn;
        float w = __expf(t > 0.f ? t : NEG * t);  // max-shift skipped: |t| small, exact ratio
        wsum += w;
        union { float4 fv; __half2 h[4]; } u;
        u.fv = ((const float4*)feat)[s];          // 16B fp16 row
#pragma unroll
        for (int q = 0; q < 4; ++q) {
            float2 hv = __half22float2(u.h[q]);
            acc[2 * q + 0] += w * hv.x;
            acc[2 * q + 1] += w * hv.y;
        }
    }
#pragma unroll
    for (int off = 8; off; off >>= 1) {
        wsum += __shfl_xor(wsum, off, 64);
#pragma unroll
        for (int k = 0; k < 8; ++k) acc[k] += __shfl_xor(acc[k], off, 64);
    }
    if (!active || l16 != 0) return;

    float inv = wsum > 0.f ? 1.f / wsum : 0.f;
    float h[8], s2 = 0.f, d2 = 0.f;
    union { float4 f; __half2 hh[4]; } u;
#pragma unroll
    for (int k = 0; k < 8; ++k) {
        float v = acc[k] * inv + b1v[k];
        h[k] = v > 0.f ? v : 0.f;
        s2 += h[k] * w2as[k];
        d2 += h[k] * w2ad[k];
    }
#pragma unroll
    for (int q = 0; q < 4; ++q) u.hh[q] = __floats2half2_rn(h[2 * q], h[2 * q + 1]);
    ((float4*)h1p)[node] = u.f;    // 16B fp16 h' row
    as2[node] = s2;
    ad2[node] = d2;
}

// Layer 2 gather on h' (8-dim), W2 applied per-node after normalization, fused log_softmax.
__global__ __launch_bounds__(256) void k_gather16(const int* __restrict__ row_ptr,
    const int* __restrict__ colsrc, const float* __restrict__ as, const float* __restrict__ ad,
    const __half* __restrict__ feat, const float* __restrict__ W2, const float* __restrict__ bias,
    float* __restrict__ outp, int n)
{
    __shared__ float w2s[128], bv[16];
    if (threadIdx.x < 128) w2s[threadIdx.x] = W2[threadIdx.x];
    else if (threadIdx.x < 144) bv[threadIdx.x - 128] = bias[threadIdx.x - 128];
    __syncthreads();

    int wid  = (blockIdx.x * 256 + threadIdx.x) >> 6;
    int lane = threadIdx.x & 63;
    int l16  = lane & 15;
    int node = wid * 4 + (lane >> 4);
    bool active = node < n;

    int start = 0, end = 0;
    float adn = 0.f;
    if (active) { start = row_ptr[node]; end = row_ptr[node + 1]; adn = ad[node]; }

    float wsum = 0.f, acc[8];
#pragma unroll
    for (int k = 0; k < 8; ++k) acc[k] = 0.f;

    for (int i = start + l16; i < end; i += 16) {
        int s = colsrc[i];
        float t = as[s] + adn;
        float w = __expf(t > 0.f ? t : NEG * t);
        wsum += w;
        union { float4 fv; __half2 h[4]; } u;
        u.fv = ((const float4*)feat)[s];          // 16B fp16 h' row
#pragma unroll
        for (int q = 0; q < 4; ++q) {
            float2 hv = __half22float2(u.h[q]);
            acc[2 * q + 0] += w * hv.x;
            acc[2 * q + 1] += w * hv.y;
        }
    }
    // reduce 9 values over 4 levels
#pragma unroll
    for (int off = 8; off; off >>= 1) {
        wsum += __shfl_xor(wsum, off, 64);
#pragma unroll
        for (int k = 0; k < 8; ++k) acc[k] += __shfl_xor(acc[k], off, 64);
    }
    if (!active) return;

    float inv = wsum > 0.f ? 1.f / wsum : 0.f;
    // each lane computes its class: o = (acc*inv) @ W2[:, l16] + b2[l16]
    float o = bv[l16];
#pragma unroll
    for (int k = 0; k < 8; ++k) o += (acc[k] * inv) * w2s[k * 16 + l16];
    // log_softmax across the 16-lane group
    float m = o;
#pragma unroll
    for (int off = 8; off; off >>= 1) m = fmaxf(m, __shfl_xor(m, off, 64));
    float se = __expf(o - m);
#pragma unroll
    for (int off = 8; off; off >>= 1) se += __shfl_xor(se, off, 64);
    float l = m + __logf(se);
    outp[(size_t)node * 16 + l16] = o - l;
}

// ============================ fallback: pure atomic path (fp32) ============================

__global__ __launch_bounds__(256) void k1_nodeF(const float* __restrict__ x,
    const float* __restrict__ W1, const float* __restrict__ a1s, const float* __restrict__ a1d,
    float* __restrict__ h1, float* __restrict__ as1, float* __restrict__ ad1, int n)
{
    __shared__ float wt[8 * 128];
    __shared__ float av[16];
    for (int i = threadIdx.x; i < 1024; i += 256) {
        int r = i >> 3, k = i & 7;
        wt[k * 128 + r] = W1[i];
    }
    if (threadIdx.x < 8)        av[threadIdx.x] = a1s[threadIdx.x];
    else if (threadIdx.x < 16)  av[threadIdx.x] = a1d[threadIdx.x - 8];
    __syncthreads();

    int lane = threadIdx.x & 31;
    int node = blockIdx.x * 8 + (threadIdx.x >> 5);
    if (node >= n) return;

    float4 xv = ((const float4*)(x + (size_t)node * 128))[lane];
    float p[8];
#pragma unroll
    for (int k = 0; k < 8; ++k) {
        float4 wv = ((const float4*)(wt + k * 128))[lane];
        p[k] = xv.x * wv.x + xv.y * wv.y + xv.z * wv.z + xv.w * wv.w;
    }
#pragma unroll
    for (int off = 16; off; off >>= 1)
#pragma unroll
        for (int k = 0; k < 8; ++k) p[k] += __shfl_down(p[k], off, 32);

    if (lane == 0) {
        float s = 0.f, d = 0.f;
#pragma unroll
        for (int k = 0; k < 8; ++k) {
            h1[(size_t)node * 8 + k] = p[k];
            s += p[k] * av[k];
            d += p[k] * av[8 + k];
        }
        as1[node] = s;
        ad1[node] = d;
    }
}

template <int F>
__global__ __launch_bounds__(256) void k_edge(const int* __restrict__ src, const int* __restrict__ dst,
    const float* __restrict__ as, const float* __restrict__ ad, const float* __restrict__ feat,
    float* __restrict__ denom, float* __restrict__ acc, int E)
{
    int e = blockIdx.x * 256 + threadIdx.x;
    if (e >= E) return;
    int s = src[e], d = dst[e];
    float t = as[s] + ad[d];
    float w = __expf(t > 0.f ? t : NEG * t);
    atomicAdd(denom + d, w);
    const float* fs = feat + (size_t)s * F;
    float* ac = acc + (size_t)d * F;
#pragma unroll
    for (int k = 0; k < F; ++k) atomicAdd(ac + k, w * fs[k]);
}

__global__ __launch_bounds__(256) void k3_node(const float* __restrict__ denom1,
    const float* __restrict__ acc1, const float* __restrict__ b1,
    const float* __restrict__ W2, const float* __restrict__ a2s, const float* __restrict__ a2d,
    float* __restrict__ g, float* __restrict__ as2, float* __restrict__ ad2, int n)
{
    __shared__ float w2[128];
    __shared__ float aa[32];
    __shared__ float bb[8];
    if (threadIdx.x < 128) w2[threadIdx.x] = W2[threadIdx.x];
    if (threadIdx.x >= 128 && threadIdx.x < 144) aa[threadIdx.x - 128] = a2s[threadIdx.x - 128];
    if (threadIdx.x >= 144 && threadIdx.x < 160) aa[16 + threadIdx.x - 144] = a2d[threadIdx.x - 144];
    if (threadIdx.x >= 160 && threadIdx.x < 168) bb[threadIdx.x - 160] = b1[threadIdx.x - 160];
    __syncthreads();

    int node = blockIdx.x * 256 + threadIdx.x;
    if (node >= n) return;
    float dn = denom1[node];
    float inv = dn > 0.f ? 1.f / dn : 0.f;
    float h[8];
#pragma unroll
    for (int k = 0; k < 8; ++k) {
        float v = acc1[(size_t)node * 8 + k] * inv + bb[k];
        h[k] = v > 0.f ? v : 0.f;
    }
    float s = 0.f, dd = 0.f;
#pragma unroll
    for (int c = 0; c < 16; ++c) {
        float gv = 0.f;
#pragma unroll
        for (int k = 0; k < 8; ++k) gv += h[k] * w2[k * 16 + c];
        g[(size_t)node * 16 + c] = gv;
        s += gv * aa[c];
        dd += gv * aa[16 + c];
    }
    as2[node] = s;
    ad2[node] = dd;
}

__global__ __launch_bounds__(256) void k5_final(const float* __restrict__ denom2,
    const float* __restrict__ acc2, const float* __restrict__ b2, float* __restrict__ out, int n)
{
    __shared__ float bb[16];
    if (threadIdx.x < 16) bb[threadIdx.x] = b2[threadIdx.x];
    __syncthreads();

    int node = blockIdx.x * 256 + threadIdx.x;
    if (node >= n) return;
    float dn = denom2[node];
    float inv = dn > 0.f ? 1.f / dn : 0.f;
    float o[16];
    float m = -1e30f;
#pragma unroll
    for (int c = 0; c < 16; ++c) {
        o[c] = acc2[(size_t)node * 16 + c] * inv + bb[c];
        m = fmaxf(m, o[c]);
    }
    float se = 0.f;
#pragma unroll
    for (int c = 0; c < 16; ++c) {
        o[c] -= m;
        se += __expf(o[c]);
    }
    float l = __logf(se);
#pragma unroll
    for (int c = 0; c < 16; ++c) out[(size_t)node * 16 + c] = o[c] - l;
}

// ============================ launch ============================

static inline char* align256(char* p) {
    return (char*)(((uintptr_t)p + 255) & ~(uintptr_t)255);
}

extern "C" void kernel_launch(void* const* d_in, const int* in_sizes, int n_in,
                              void* d_out, int out_size, void* d_ws, size_t ws_size,
                              hipStream_t stream)
{
    const float* x    = (const float*)d_in[0];
    const int*   eidx = (const int*)d_in[1];
    const float* W1   = (const float*)d_in[2];
    const float* a1s  = (const float*)d_in[3];
    const float* a1d  = (const float*)d_in[4];
    const float* b1   = (const float*)d_in[5];
    const float* W2   = (const float*)d_in[6];
    const float* a2s  = (const float*)d_in[7];
    const float* a2d  = (const float*)d_in[8];
    const float* b2   = (const float*)d_in[9];
    float* out = (float*)d_out;

    const int n = in_sizes[0] / 128;
    const int E = in_sizes[1] / 2;
    const int* src = eidx;
    const int* dst = eidx + E;
    const int NB = (n + BUCKN - 1) >> CSHIFT;
    const int NBLK = (E + CHUNK - 1) / CHUNK;

    // ---- tier-0: bucket-sort CSR (gmat/pbaseRel aliased into colsrc) + fp16 gathers ----
    {
        char* p = (char*)d_ws;
        char* p0 = p;
        unsigned* stage = (unsigned*)p;  p = align256(p + (size_t)E * 4);
        int* colsrc  = (int*)p;          p = align256(p + (size_t)E * 4);
        int* total   = (int*)p;          p = align256(p + (size_t)NB * 4);
        int* cptr    = (int*)p;          p = align256(p + (size_t)(NB + 1) * 4);
        int* row_ptr = (int*)p;          p = align256(p + (size_t)(n + 1) * 4);
        __half* h1   = (__half*)p;       p = align256(p + (size_t)8 * n * 2);
        __half* h1p  = (__half*)p;       p = align256(p + (size_t)8 * n * 2);
        float* as1   = (float*)p;        p = align256(p + (size_t)n * 4);
        float* ad1   = (float*)p;        p = align256(p + (size_t)n * 4);
        float* as2   = (float*)p;        p = align256(p + (size_t)n * 4);
        float* ad2   = (float*)p;        p = align256(p + (size_t)n * 4);
        size_t needed = (size_t)(p - p0);

        int* gmat     = colsrc;                       // alias (dead before p2)
        int* pbaseRel = (int*)align256((char*)(colsrc + (size_t)NBLK * NB));

        bool alias_ok = ((size_t)2 * NBLK * NB + 64) <= (size_t)E;

        if (n <= 131072 && NB <= MAXNB && alias_ok && ws_size >= needed) {
            k1_node<<<(n + 7) / 8, 256, 0, stream>>>(x, W1, a1s, a1d, h1, as1, ad1, n);

            p1a<<<NBLK, 256, 0, stream>>>(dst, gmat, E, NB);
            pcol<<<NB, 256, 0, stream>>>(gmat, pbaseRel, total, NBLK, NB);
            ptot<<<1, 512, 0, stream>>>(total, cptr, row_ptr, NB, n, E);
            p1bW<<<NBLK, 256, 0, stream>>>(src, dst, cptr, pbaseRel, stage, E, NB);
            p2<<<NB, 512, 0, stream>>>(stage, cptr, colsrc, row_ptr, n);

            // 16 lanes per node, 4 nodes per wave
            const int gblocks = ((size_t)n * 16 + 255) / 256;
            k_gather8f<<<gblocks, 256, 0, stream>>>(row_ptr, colsrc, as1, ad1, h1,
                                                    b1, W2, a2s, a2d, h1p, as2, ad2, n);
            k_gather16<<<gblocks, 256, 0, stream>>>(row_ptr, colsrc, as2, ad2, h1p, W2, b2, out, n);
            return;
        }
    }

    // ---- fallback: pure atomic path (fp32) ----
    {
        float* ws     = (float*)d_ws;
        float* denom1 = ws;
        float* acc1   = ws + (size_t)n;
        float* denom2 = ws + (size_t)9 * n;
        float* acc2   = ws + (size_t)10 * n;
        float* h1     = ws + (size_t)26 * n;
        float* as1    = ws + (size_t)34 * n;
        float* ad1    = ws + (size_t)35 * n;
        float* g      = ws + (size_t)36 * n;
        float* as2    = ws + (size_t)52 * n;
        float* ad2    = ws + (size_t)53 * n;

        hipMemsetAsync(ws, 0, (size_t)26 * n * sizeof(float), stream);
        k1_nodeF<<<(n + 7) / 8, 256, 0, stream>>>(x, W1, a1s, a1d, h1, as1, ad1, n);
        k_edge<8><<<(E + 255) / 256, 256, 0, stream>>>(src, dst, as1, ad1, h1, denom1, acc1, E);
        k3_node<<<(n + 255) / 256, 256, 0, stream>>>(denom1, acc1, b1, W2, a2s, a2d, g, as2, ad2, n);
        k_edge<16><<<(E + 255) / 256, 256, 0, stream>>>(src, dst, as2, ad2, g, denom2, acc2, E);
        k5_final<<<(n + 255) / 256, 256, 0, stream>>>(denom2, acc2, b2, out, n);
    }
}

// Round 16
// 219.084 us; speedup vs baseline: 5.6856x; 1.1869x over previous
//
#include <hip/hip_runtime.h>
#include <hip/hip_fp16.h>
#include <math.h>
#include <stdint.h>

#define NEG 0.2f
#define CSHIFT 9
#define BUCKN (1 << CSHIFT)     // 512 nodes per bucket
#define MAXNB 256               // NB <= 256 for n <= 131072 (CSHIFT=9)
#define CHUNK 4096

// ============================ node transform (packed 32B rows: 8 fp16 h | fp32 alpha_s | pad) ============================

__global__ __launch_bounds__(256) void k1_node(const float* __restrict__ x,
    const float* __restrict__ W1, const float* __restrict__ a1s, const float* __restrict__ a1d,
    float4* __restrict__ h1pk, float* __restrict__ ad1, int n)
{
    __shared__ float wt[8 * 128];
    __shared__ float av[16];
    for (int i = threadIdx.x; i < 1024; i += 256) {
        int r = i >> 3, k = i & 7;
        wt[k * 128 + r] = W1[i];
    }
    if (threadIdx.x < 8)        av[threadIdx.x] = a1s[threadIdx.x];
    else if (threadIdx.x < 16)  av[threadIdx.x] = a1d[threadIdx.x - 8];
    __syncthreads();

    int lane = threadIdx.x & 31;
    int node = blockIdx.x * 8 + (threadIdx.x >> 5);
    if (node >= n) return;

    float4 xv = ((const float4*)(x + (size_t)node * 128))[lane];
    float p[8];
#pragma unroll
    for (int k = 0; k < 8; ++k) {
        float4 wv = ((const float4*)(wt + k * 128))[lane];
        p[k] = xv.x * wv.x + xv.y * wv.y + xv.z * wv.z + xv.w * wv.w;
    }
#pragma unroll
    for (int off = 16; off; off >>= 1)
#pragma unroll
        for (int k = 0; k < 8; ++k) p[k] += __shfl_down(p[k], off, 32);

    if (lane == 0) {
        float s = 0.f, d = 0.f;
        union { float4 f; __half2 h[4]; } u;
#pragma unroll
        for (int k = 0; k < 8; ++k) {
            s += p[k] * av[k];
            d += p[k] * av[8 + k];
        }
#pragma unroll
        for (int q = 0; q < 4; ++q) u.h[q] = __floats2half2_rn(p[2 * q], p[2 * q + 1]);
        h1pk[2 * (size_t)node]     = u.f;                        // 16B fp16 h row
        h1pk[2 * (size_t)node + 1] = make_float4(s, 0.f, 0.f, 0.f);  // alpha_s
        ad1[node] = d;
    }
}

// ============================ bucket-sort CSR build (all-parallel, atomic-free) ============================

__global__ __launch_bounds__(256) void p1a(const int* __restrict__ dst, int* __restrict__ gmat,
                                           int E, int NB)
{
    __shared__ int h[MAXNB];
    for (int i = threadIdx.x; i < NB; i += 256) h[i] = 0;
    __syncthreads();
    int base = blockIdx.x * CHUNK;
    int end = base + CHUNK; if (end > E) end = E;
    for (int i = base + threadIdx.x; i < end; i += 256)
        atomicAdd(&h[dst[i] >> CSHIFT], 1);
    __syncthreads();
    int* row = gmat + (size_t)blockIdx.x * NB;
    for (int i = threadIdx.x; i < NB; i += 256) row[i] = h[i];
}

__global__ __launch_bounds__(256) void pcol(const int* __restrict__ gmat, int* __restrict__ pbaseRel,
    int* __restrict__ total, int NBLK, int NB)
{
    __shared__ int wsum[4];
    int b = blockIdx.x;
    int tid = threadIdx.x;
    int chunk = (NBLK + 255) >> 8;
    int k0 = tid * chunk;
    int s = 0;
    for (int j = 0; j < chunk; ++j) {
        int k = k0 + j;
        if (k < NBLK) s += gmat[(size_t)k * NB + b];
    }
    int lane = tid & 63, w = tid >> 6;
    int sc = s;
#pragma unroll
    for (int off = 1; off < 64; off <<= 1) {
        int t = __shfl_up(sc, off, 64);
        if (lane >= off) sc += t;
    }
    if (lane == 63) wsum[w] = sc;
    __syncthreads();
    if (tid == 0) { int a = 0; for (int i = 0; i < 4; ++i) { int t = wsum[i]; wsum[i] = a; a += t; } }
    __syncthreads();
    int run = sc - s + wsum[w];
    for (int j = 0; j < chunk; ++j) {
        int k = k0 + j;
        if (k < NBLK) {
            int gv = gmat[(size_t)k * NB + b];
            pbaseRel[(size_t)k * NB + b] = run;
            run += gv;
        }
    }
    if (tid == 255) total[b] = run;
}

__global__ __launch_bounds__(512) void ptot(const int* __restrict__ total, int* __restrict__ cptr,
                                            int* __restrict__ row_ptr, int NB, int n, int E)
{
    __shared__ int wsum[8];
    int b = threadIdx.x;
    int v = b < NB ? total[b] : 0;
    int lane = b & 63, w = b >> 6;
    int s = v;
#pragma unroll
    for (int off = 1; off < 64; off <<= 1) {
        int t = __shfl_up(s, off, 64);
        if (lane >= off) s += t;
    }
    if (lane == 63) wsum[w] = s;
    __syncthreads();
    if (b == 0) { int a = 0; for (int i = 0; i < 8; ++i) { int t = wsum[i]; wsum[i] = a; a += t; } }
    __syncthreads();
    int excl = s - v + wsum[w];
    if (b < NB) cptr[b] = excl;
    if (b == 0) { cptr[NB] = E; row_ptr[n] = E; }
}

// pass 1b: LDS write-combining; histogram READ from gmat (no re-hist).
__global__ __launch_bounds__(256) void p1bW(const int* __restrict__ src, const int* __restrict__ dst,
    const int* __restrict__ gmat, const int* __restrict__ cptr, const int* __restrict__ pbaseRel,
    unsigned* __restrict__ stage, int E, int NB)
{
    __shared__ int lbase[MAXNB], bbase[MAXNB], ccur[MAXNB];
    __shared__ unsigned bufp[CHUNK];
    __shared__ unsigned short bufb[CHUNK];
    __shared__ int wsum[4];
    int tid = threadIdx.x;
    if (tid < NB) ccur[tid] = 0;

    int base = blockIdx.x * CHUNK;
    int end = base + CHUNK; if (end > E) end = E;
    int cnt = end - base;

    // exclusive scan of this block's histogram row (from gmat)
    int v = (tid < NB) ? gmat[(size_t)blockIdx.x * NB + tid] : 0;
    int lane = tid & 63, w = tid >> 6;
    int sc = v;
#pragma unroll
    for (int off = 1; off < 64; off <<= 1) {
        int t = __shfl_up(sc, off, 64);
        if (lane >= off) sc += t;
    }
    if (lane == 63) wsum[w] = sc;
    __syncthreads();
    if (tid == 0) { int a = 0; for (int i = 0; i < 4; ++i) { int t = wsum[i]; wsum[i] = a; a += t; } }
    __syncthreads();
    if (tid < NB) {
        lbase[tid] = sc - v + wsum[w];
        bbase[tid] = cptr[tid] + pbaseRel[(size_t)blockIdx.x * NB + tid];
    }
    __syncthreads();

    // LDS scatter (random LDS, cheap)
    for (int i = base + tid; i < end; i += 256) {
        int d = dst[i];
        int b = d >> CSHIFT;
        int off = atomicAdd(&ccur[b], 1);
        int pos = lbase[b] + off;
        bufp[pos] = ((unsigned)(d & (BUCKN - 1)) << 17) | (unsigned)src[i];
        bufb[pos] = (unsigned short)b;
    }
    __syncthreads();

    // flush: consecutive local positions within a bucket -> consecutive global
    for (int i = tid; i < cnt; i += 256) {
        int b = bufb[i];
        stage[bbase[b] + (i - lbase[b])] = bufp[i];
    }
}

// pass 2: per-bucket fine counting-sort (512-node buckets) -> colsrc + row_ptr
__global__ __launch_bounds__(512) void p2(const unsigned* __restrict__ stage,
    const int* __restrict__ cptr, int* __restrict__ colsrc, int* __restrict__ row_ptr, int n)
{
    int b = blockIdx.x;
    int nbase = b << CSHIFT;
    int NN = n - nbase; if (NN > BUCKN) NN = BUCKN;
    __shared__ int h[BUCKN], bps[BUCKN], cc[BUCKN];
    __shared__ int wsum[8];
    int tid = threadIdx.x;
    h[tid] = 0; cc[tid] = 0;
    __syncthreads();
    int s0 = cptr[b], s1 = cptr[b + 1];
    for (int i = s0 + tid; i < s1; i += 512)
        atomicAdd(&h[stage[i] >> 17], 1);
    __syncthreads();
    int v = h[tid];
    int lane = tid & 63, w = tid >> 6;
    int sc = v;
#pragma unroll
    for (int off = 1; off < 64; off <<= 1) {
        int t = __shfl_up(sc, off, 64);
        if (lane >= off) sc += t;
    }
    if (lane == 63) wsum[w] = sc;
    __syncthreads();
    if (tid == 0) { int a = 0; for (int i = 0; i < 8; ++i) { int t = wsum[i]; wsum[i] = a; a += t; } }
    __syncthreads();
    int excl = sc - v + wsum[w];
    bps[tid] = s0 + excl;
    if (tid < NN) row_ptr[nbase + tid] = s0 + excl;
    __syncthreads();
    for (int i = s0 + tid; i < s1; i += 512) {
        unsigned p = stage[i];
        int f = p >> 17;
        int off = atomicAdd(&cc[f], 1);
        colsrc[bps[f] + off] = (int)(p & 0x1FFFFu);
    }
}

// ============================ gathers (packed 32B rows, 16 lanes/node, 4 nodes/wave) ============================

// Layer 1 gather -> h' packed (16B fp16 h' | fp32 as2 | pad); ad2 separate.
// as2/ad2 via precomputed W2@a2s / W2@a2d (aggregation commutes with W2).
__global__ __launch_bounds__(256) void k_gather8f(const int* __restrict__ row_ptr,
    const int* __restrict__ colsrc, const float4* __restrict__ featpk, const float* __restrict__ ad,
    const float* __restrict__ b1, const float* __restrict__ W2,
    const float* __restrict__ a2s, const float* __restrict__ a2d,
    float4* __restrict__ outpk, float* __restrict__ ad2, int n)
{
    __shared__ float w2as[8], w2ad[8], b1v[8];
    if (threadIdx.x < 8) {
        float s = 0.f, d = 0.f;
#pragma unroll
        for (int c = 0; c < 16; ++c) {
            float wv = W2[threadIdx.x * 16 + c];
            s += wv * a2s[c];
            d += wv * a2d[c];
        }
        w2as[threadIdx.x] = s;
        w2ad[threadIdx.x] = d;
        b1v[threadIdx.x] = b1[threadIdx.x];
    }
    __syncthreads();

    int wid  = (blockIdx.x * 256 + threadIdx.x) >> 6;
    int lane = threadIdx.x & 63;
    int l16  = lane & 15;
    int node = wid * 4 + (lane >> 4);
    bool active = node < n;

    int start = 0, end = 0;
    float adn = 0.f;
    if (active) { start = row_ptr[node]; end = row_ptr[node + 1]; adn = ad[node]; }

    float wsum = 0.f, acc[8];
#pragma unroll
    for (int k = 0; k < 8; ++k) acc[k] = 0.f;

    for (int i = start + l16; i < end; i += 16) {
        int s = colsrc[i];
        union { float4 fv; __half2 h[4]; } u;
        u.fv = featpk[2 * (size_t)s];            // 16B fp16 h row
        float4 meta = featpk[2 * (size_t)s + 1]; // alpha_s in .x (same 32B line)
        float t = meta.x + adn;
        float w = __expf(t > 0.f ? t : NEG * t); // max-shift skipped: |t| small, exact ratio
        wsum += w;
#pragma unroll
        for (int q = 0; q < 4; ++q) {
            float2 hv = __half22float2(u.h[q]);
            acc[2 * q + 0] += w * hv.x;
            acc[2 * q + 1] += w * hv.y;
        }
    }
#pragma unroll
    for (int off = 8; off; off >>= 1) {
        wsum += __shfl_xor(wsum, off, 64);
#pragma unroll
        for (int k = 0; k < 8; ++k) acc[k] += __shfl_xor(acc[k], off, 64);
    }
    if (!active || l16 != 0) return;

    float inv = wsum > 0.f ? 1.f / wsum : 0.f;
    float h[8], s2 = 0.f, d2 = 0.f;
    union { float4 f; __half2 hh[4]; } u;
#pragma unroll
    for (int k = 0; k < 8; ++k) {
        float v = acc[k] * inv + b1v[k];
        h[k] = v > 0.f ? v : 0.f;
        s2 += h[k] * w2as[k];
        d2 += h[k] * w2ad[k];
    }
#pragma unroll
    for (int q = 0; q < 4; ++q) u.hh[q] = __floats2half2_rn(h[2 * q], h[2 * q + 1]);
    outpk[2 * (size_t)node]     = u.f;
    outpk[2 * (size_t)node + 1] = make_float4(s2, 0.f, 0.f, 0.f);
    ad2[node] = d2;
}

// Layer 2 gather on packed h' (8-dim), W2 per-node after normalization, fused log_softmax.
__global__ __launch_bounds__(256) void k_gather16(const int* __restrict__ row_ptr,
    const int* __restrict__ colsrc, const float4* __restrict__ featpk, const float* __restrict__ ad,
    const float* __restrict__ W2, const float* __restrict__ bias, float* __restrict__ outp, int n)
{
    __shared__ float w2s[128], bv[16];
    if (threadIdx.x < 128) w2s[threadIdx.x] = W2[threadIdx.x];
    else if (threadIdx.x < 144) bv[threadIdx.x - 128] = bias[threadIdx.x - 128];
    __syncthreads();

    int wid  = (blockIdx.x * 256 + threadIdx.x) >> 6;
    int lane = threadIdx.x & 63;
    int l16  = lane & 15;
    int node = wid * 4 + (lane >> 4);
    bool active = node < n;

    int start = 0, end = 0;
    float adn = 0.f;
    if (active) { start = row_ptr[node]; end = row_ptr[node + 1]; adn = ad[node]; }

    float wsum = 0.f, acc[8];
#pragma unroll
    for (int k = 0; k < 8; ++k) acc[k] = 0.f;

    for (int i = start + l16; i < end; i += 16) {
        int s = colsrc[i];
        union { float4 fv; __half2 h[4]; } u;
        u.fv = featpk[2 * (size_t)s];
        float4 meta = featpk[2 * (size_t)s + 1];
        float t = meta.x + adn;
        float w = __expf(t > 0.f ? t : NEG * t);
        wsum += w;
#pragma unroll
        for (int q = 0; q < 4; ++q) {
            float2 hv = __half22float2(u.h[q]);
            acc[2 * q + 0] += w * hv.x;
            acc[2 * q + 1] += w * hv.y;
        }
    }
#pragma unroll
    for (int off = 8; off; off >>= 1) {
        wsum += __shfl_xor(wsum, off, 64);
#pragma unroll
        for (int k = 0; k < 8; ++k) acc[k] += __shfl_xor(acc[k], off, 64);
    }
    if (!active) return;

    float inv = wsum > 0.f ? 1.f / wsum : 0.f;
    float o = bv[l16];
#pragma unroll
    for (int k = 0; k < 8; ++k) o += (acc[k] * inv) * w2s[k * 16 + l16];
    float m = o;
#pragma unroll
    for (int off = 8; off; off >>= 1) m = fmaxf(m, __shfl_xor(m, off, 64));
    float se = __expf(o - m);
#pragma unroll
    for (int off = 8; off; off >>= 1) se += __shfl_xor(se, off, 64);
    float l = m + __logf(se);
    outp[(size_t)node * 16 + l16] = o - l;
}

// ============================ fallback: pure atomic path (fp32) ============================

__global__ __launch_bounds__(256) void k1_nodeF(const float* __restrict__ x,
    const float* __restrict__ W1, const float* __restrict__ a1s, const float* __restrict__ a1d,
    float* __restrict__ h1, float* __restrict__ as1, float* __restrict__ ad1, int n)
{
    __shared__ float wt[8 * 128];
    __shared__ float av[16];
    for (int i = threadIdx.x; i < 1024; i += 256) {
        int r = i >> 3, k = i & 7;
        wt[k * 128 + r] = W1[i];
    }
    if (threadIdx.x < 8)        av[threadIdx.x] = a1s[threadIdx.x];
    else if (threadIdx.x < 16)  av[threadIdx.x] = a1d[threadIdx.x - 8];
    __syncthreads();

    int lane = threadIdx.x & 31;
    int node = blockIdx.x * 8 + (threadIdx.x >> 5);
    if (node >= n) return;

    float4 xv = ((const float4*)(x + (size_t)node * 128))[lane];
    float p[8];
#pragma unroll
    for (int k = 0; k < 8; ++k) {
        float4 wv = ((const float4*)(wt + k * 128))[lane];
        p[k] = xv.x * wv.x + xv.y * wv.y + xv.z * wv.z + xv.w * wv.w;
    }
#pragma unroll
    for (int off = 16; off; off >>= 1)
#pragma unroll
        for (int k = 0; k < 8; ++k) p[k] += __shfl_down(p[k], off, 32);

    if (lane == 0) {
        float s = 0.f, d = 0.f;
#pragma unroll
        for (int k = 0; k < 8; ++k) {
            h1[(size_t)node * 8 + k] = p[k];
            s += p[k] * av[k];
            d += p[k] * av[8 + k];
        }
        as1[node] = s;
        ad1[node] = d;
    }
}

template <int F>
__global__ __launch_bounds__(256) void k_edge(const int* __restrict__ src, const int* __restrict__ dst,
    const float* __restrict__ as, const float* __restrict__ ad, const float* __restrict__ feat,
    float* __restrict__ denom, float* __restrict__ acc, int E)
{
    int e = blockIdx.x * 256 + threadIdx.x;
    if (e >= E) return;
    int s = src[e], d = dst[e];
    float t = as[s] + ad[d];
    float w = __expf(t > 0.f ? t : NEG * t);
    atomicAdd(denom + d, w);
    const float* fs = feat + (size_t)s * F;
    float* ac = acc + (size_t)d * F;
#pragma unroll
    for (int k = 0; k < F; ++k) atomicAdd(ac + k, w * fs[k]);
}

__global__ __launch_bounds__(256) void k3_node(const float* __restrict__ denom1,
    const float* __restrict__ acc1, const float* __restrict__ b1,
    const float* __restrict__ W2, const float* __restrict__ a2s, const float* __restrict__ a2d,
    float* __restrict__ g, float* __restrict__ as2, float* __restrict__ ad2, int n)
{
    __shared__ float w2[128];
    __shared__ float aa[32];
    __shared__ float bb[8];
    if (threadIdx.x < 128) w2[threadIdx.x] = W2[threadIdx.x];
    if (threadIdx.x >= 128 && threadIdx.x < 144) aa[threadIdx.x - 128] = a2s[threadIdx.x - 128];
    if (threadIdx.x >= 144 && threadIdx.x < 160) aa[16 + threadIdx.x - 144] = a2d[threadIdx.x - 144];
    if (threadIdx.x >= 160 && threadIdx.x < 168) bb[threadIdx.x - 160] = b1[threadIdx.x - 160];
    __syncthreads();

    int node = blockIdx.x * 256 + threadIdx.x;
    if (node >= n) return;
    float dn = denom1[node];
    float inv = dn > 0.f ? 1.f / dn : 0.f;
    float h[8];
#pragma unroll
    for (int k = 0; k < 8; ++k) {
        float v = acc1[(size_t)node * 8 + k] * inv + bb[k];
        h[k] = v > 0.f ? v : 0.f;
    }
    float s = 0.f, dd = 0.f;
#pragma unroll
    for (int c = 0; c < 16; ++c) {
        float gv = 0.f;
#pragma unroll
        for (int k = 0; k < 8; ++k) gv += h[k] * w2[k * 16 + c];
        g[(size_t)node * 16 + c] = gv;
        s += gv * aa[c];
        dd += gv * aa[16 + c];
    }
    as2[node] = s;
    ad2[node] = dd;
}

__global__ __launch_bounds__(256) void k5_final(const float* __restrict__ denom2,
    const float* __restrict__ acc2, const float* __restrict__ b2, float* __restrict__ out, int n)
{
    __shared__ float bb[16];
    if (threadIdx.x < 16) bb[threadIdx.x] = b2[threadIdx.x];
    __syncthreads();

    int node = blockIdx.x * 256 + threadIdx.x;
    if (node >= n) return;
    float dn = denom2[node];
    float inv = dn > 0.f ? 1.f / dn : 0.f;
    float o[16];
    float m = -1e30f;
#pragma unroll
    for (int c = 0; c < 16; ++c) {
        o[c] = acc2[(size_t)node * 16 + c] * inv + bb[c];
        m = fmaxf(m, o[c]);
    }
    float se = 0.f;
#pragma unroll
    for (int c = 0; c < 16; ++c) {
        o[c] -= m;
        se += __expf(o[c]);
    }
    float l = __logf(se);
#pragma unroll
    for (int c = 0; c < 16; ++c) out[(size_t)node * 16 + c] = o[c] - l;
}

// ============================ launch ============================

static inline char* align256(char* p) {
    return (char*)(((uintptr_t)p + 255) & ~(uintptr_t)255);
}

extern "C" void kernel_launch(void* const* d_in, const int* in_sizes, int n_in,
                              void* d_out, int out_size, void* d_ws, size_t ws_size,
                              hipStream_t stream)
{
    const float* x    = (const float*)d_in[0];
    const int*   eidx = (const int*)d_in[1];
    const float* W1   = (const float*)d_in[2];
    const float* a1s  = (const float*)d_in[3];
    const float* a1d  = (const float*)d_in[4];
    const float* b1   = (const float*)d_in[5];
    const float* W2   = (const float*)d_in[6];
    const float* a2s  = (const float*)d_in[7];
    const float* a2d  = (const float*)d_in[8];
    const float* b2   = (const float*)d_in[9];
    float* out = (float*)d_out;

    const int n = in_sizes[0] / 128;
    const int E = in_sizes[1] / 2;
    const int* src = eidx;
    const int* dst = eidx + E;
    const int NB = (n + BUCKN - 1) >> CSHIFT;
    const int NBLK = (E + CHUNK - 1) / CHUNK;

    // ---- tier-0: bucket-sort CSR (gmat/pbaseRel aliased into colsrc) + packed fp16 gathers ----
    {
        char* p = (char*)d_ws;
        char* p0 = p;
        unsigned* stage = (unsigned*)p;  p = align256(p + (size_t)E * 4);
        int* colsrc  = (int*)p;          p = align256(p + (size_t)E * 4);
        int* total   = (int*)p;          p = align256(p + (size_t)NB * 4);
        int* cptr    = (int*)p;          p = align256(p + (size_t)(NB + 1) * 4);
        int* row_ptr = (int*)p;          p = align256(p + (size_t)(n + 1) * 4);
        float4* h1pk  = (float4*)p;      p = align256(p + (size_t)n * 32);
        float4* h1ppk = (float4*)p;      p = align256(p + (size_t)n * 32);
        float* ad1   = (float*)p;        p = align256(p + (size_t)n * 4);
        float* ad2   = (float*)p;        p = align256(p + (size_t)n * 4);
        size_t needed = (size_t)(p - p0);

        int* gmat     = colsrc;                       // alias (dead before p2)
        int* pbaseRel = (int*)align256((char*)(colsrc + (size_t)NBLK * NB));

        bool alias_ok = ((size_t)2 * NBLK * NB + 64) <= (size_t)E;

        if (n <= 131072 && NB <= MAXNB && alias_ok && ws_size >= needed) {
            k1_node<<<(n + 7) / 8, 256, 0, stream>>>(x, W1, a1s, a1d, h1pk, ad1, n);

            p1a<<<NBLK, 256, 0, stream>>>(dst, gmat, E, NB);
            pcol<<<NB, 256, 0, stream>>>(gmat, pbaseRel, total, NBLK, NB);
            ptot<<<1, 512, 0, stream>>>(total, cptr, row_ptr, NB, n, E);
            p1bW<<<NBLK, 256, 0, stream>>>(src, dst, gmat, cptr, pbaseRel, stage, E, NB);
            p2<<<NB, 512, 0, stream>>>(stage, cptr, colsrc, row_ptr, n);

            // 16 lanes per node, 4 nodes per wave
            const int gblocks = ((size_t)n * 16 + 255) / 256;
            k_gather8f<<<gblocks, 256, 0, stream>>>(row_ptr, colsrc, h1pk, ad1,
                                                    b1, W2, a2s, a2d, h1ppk, ad2, n);
            k_gather16<<<gblocks, 256, 0, stream>>>(row_ptr, colsrc, h1ppk, ad2, W2, b2, out, n);
            return;
        }
    }

    // ---- fallback: pure atomic path (fp32) ----
    {
        float* ws     = (float*)d_ws;
        float* denom1 = ws;
        float* acc1   = ws + (size_t)n;
        float* denom2 = ws + (size_t)9 * n;
        float* acc2   = ws + (size_t)10 * n;
        float* h1     = ws + (size_t)26 * n;
        float* as1    = ws + (size_t)34 * n;
        float* ad1    = ws + (size_t)35 * n;
        float* g      = ws + (size_t)36 * n;
        float* as2    = ws + (size_t)52 * n;
        float* ad2    = ws + (size_t)53 * n;

        hipMemsetAsync(ws, 0, (size_t)26 * n * sizeof(float), stream);
        k1_nodeF<<<(n + 7) / 8, 256, 0, stream>>>(x, W1, a1s, a1d, h1, as1, ad1, n);
        k_edge<8><<<(E + 255) / 256, 256, 0, stream>>>(src, dst, as1, ad1, h1, denom1, acc1, E);
        k3_node<<<(n + 255) / 256, 256, 0, stream>>>(denom1, acc1, b1, W2, a2s, a2d, g, as2, ad2, n);
        k_edge<16><<<(E + 255) / 256, 256, 0, stream>>>(src, dst, as2, ad2, g, denom2, acc2, E);
        k5_final<<<(n + 255) / 256, 256, 0, stream>>>(denom2, acc2, b2, out, n);
    }
}

// Round 17
// 215.261 us; speedup vs baseline: 5.7866x; 1.0178x over previous
//
#include <hip/hip_runtime.h>
#include <hip/hip_fp16.h>
#include <math.h>
#include <stdint.h>

#define NEG 0.2f
#define CSHIFT 7
#define BUCKN (1 << CSHIFT)     // 128 nodes per bucket
#define MAXNB 1024              // NB <= 1024 for n <= 131072 (CSHIFT=7)
#define CHUNK 4096
#define FBUF 9216               // staged colsrc tile (mean span 8185 @ n=100k/E=6.4M)

// ============================ node transform (packed 32B rows: 8 fp16 h | fp32 alpha_s | pad) ============================

__global__ __launch_bounds__(256) void k1_node(const float* __restrict__ x,
    const float* __restrict__ W1, const float* __restrict__ a1s, const float* __restrict__ a1d,
    float4* __restrict__ h1pk, float* __restrict__ ad1, int n)
{
    __shared__ float wt[8 * 128];
    __shared__ float av[16];
    for (int i = threadIdx.x; i < 1024; i += 256) {
        int r = i >> 3, k = i & 7;
        wt[k * 128 + r] = W1[i];
    }
    if (threadIdx.x < 8)        av[threadIdx.x] = a1s[threadIdx.x];
    else if (threadIdx.x < 16)  av[threadIdx.x] = a1d[threadIdx.x - 8];
    __syncthreads();

    int lane = threadIdx.x & 31;
    int node = blockIdx.x * 8 + (threadIdx.x >> 5);
    if (node >= n) return;

    float4 xv = ((const float4*)(x + (size_t)node * 128))[lane];
    float p[8];
#pragma unroll
    for (int k = 0; k < 8; ++k) {
        float4 wv = ((const float4*)(wt + k * 128))[lane];
        p[k] = xv.x * wv.x + xv.y * wv.y + xv.z * wv.z + xv.w * wv.w;
    }
#pragma unroll
    for (int off = 16; off; off >>= 1)
#pragma unroll
        for (int k = 0; k < 8; ++k) p[k] += __shfl_down(p[k], off, 32);

    if (lane == 0) {
        float s = 0.f, d = 0.f;
        union { float4 f; __half2 h[4]; } u;
#pragma unroll
        for (int k = 0; k < 8; ++k) {
            s += p[k] * av[k];
            d += p[k] * av[8 + k];
        }
#pragma unroll
        for (int q = 0; q < 4; ++q) u.h[q] = __floats2half2_rn(p[2 * q], p[2 * q + 1]);
        h1pk[2 * (size_t)node]     = u.f;                        // 16B fp16 h row
        h1pk[2 * (size_t)node + 1] = make_float4(s, 0.f, 0.f, 0.f);  // alpha_s
        ad1[node] = d;
    }
}

// ============================ bucket-sort CSR build (all-parallel, atomic-free) ============================

__global__ __launch_bounds__(256) void p1a(const int* __restrict__ dst, int* __restrict__ gmat,
                                           int E, int NB)
{
    __shared__ int h[MAXNB];
    for (int i = threadIdx.x; i < NB; i += 256) h[i] = 0;
    __syncthreads();
    int base = blockIdx.x * CHUNK;
    int end = base + CHUNK; if (end > E) end = E;
    for (int i = base + threadIdx.x; i < end; i += 256)
        atomicAdd(&h[dst[i] >> CSHIFT], 1);
    __syncthreads();
    int* row = gmat + (size_t)blockIdx.x * NB;
    for (int i = threadIdx.x; i < NB; i += 256) row[i] = h[i];
}

__global__ __launch_bounds__(256) void pcol(const int* __restrict__ gmat, int* __restrict__ pbaseRel,
    int* __restrict__ total, int NBLK, int NB)
{
    __shared__ int wsum[4];
    int b = blockIdx.x;
    int tid = threadIdx.x;
    int chunk = (NBLK + 255) >> 8;
    int k0 = tid * chunk;
    int s = 0;
    for (int j = 0; j < chunk; ++j) {
        int k = k0 + j;
        if (k < NBLK) s += gmat[(size_t)k * NB + b];
    }
    int lane = tid & 63, w = tid >> 6;
    int sc = s;
#pragma unroll
    for (int off = 1; off < 64; off <<= 1) {
        int t = __shfl_up(sc, off, 64);
        if (lane >= off) sc += t;
    }
    if (lane == 63) wsum[w] = sc;
    __syncthreads();
    if (tid == 0) { int a = 0; for (int i = 0; i < 4; ++i) { int t = wsum[i]; wsum[i] = a; a += t; } }
    __syncthreads();
    int run = sc - s + wsum[w];
    for (int j = 0; j < chunk; ++j) {
        int k = k0 + j;
        if (k < NBLK) {
            int gv = gmat[(size_t)k * NB + b];
            pbaseRel[(size_t)k * NB + b] = run;
            run += gv;
        }
    }
    if (tid == 255) total[b] = run;
}

// scan bucket totals -> cptr (single block, chunked over NB <= MAXNB)
__global__ __launch_bounds__(512) void ptot(const int* __restrict__ total, int* __restrict__ cptr,
                                            int* __restrict__ row_ptr, int NB, int n, int E)
{
    __shared__ int wsum[8];
    int tid = threadIdx.x;
    int chunk = (NB + 511) >> 9;
    int k0 = tid * chunk;
    int s = 0;
    for (int j = 0; j < chunk; ++j) {
        int k = k0 + j;
        if (k < NB) s += total[k];
    }
    int lane = tid & 63, w = tid >> 6;
    int sc = s;
#pragma unroll
    for (int off = 1; off < 64; off <<= 1) {
        int t = __shfl_up(sc, off, 64);
        if (lane >= off) sc += t;
    }
    if (lane == 63) wsum[w] = sc;
    __syncthreads();
    if (tid == 0) { int a = 0; for (int i = 0; i < 8; ++i) { int t = wsum[i]; wsum[i] = a; a += t; } }
    __syncthreads();
    int run = sc - s + wsum[w];
    for (int j = 0; j < chunk; ++j) {
        int k = k0 + j;
        if (k < NB) { cptr[k] = run; run += total[k]; }
    }
    if (tid == 0) { cptr[NB] = E; row_ptr[n] = E; }
}

// pass 1b: LDS write-combining; histogram read from gmat; chunked scan (NB up to 1024).
__global__ __launch_bounds__(256) void p1bW(const int* __restrict__ src, const int* __restrict__ dst,
    const int* __restrict__ gmat, const int* __restrict__ cptr, const int* __restrict__ pbaseRel,
    unsigned* __restrict__ stage, int E, int NB)
{
    __shared__ int lbase[MAXNB], bbase[MAXNB], ccur[MAXNB];
    __shared__ unsigned bufp[CHUNK];
    __shared__ unsigned short bufb[CHUNK];
    __shared__ int wsum[4];
    int tid = threadIdx.x;
    const int* grow = gmat + (size_t)blockIdx.x * NB;
    const int* prow = pbaseRel + (size_t)blockIdx.x * NB;

    int base = blockIdx.x * CHUNK;
    int end = base + CHUNK; if (end > E) end = E;
    int cnt = end - base;

    // chunked exclusive scan of this block's histogram row
    int chunkb = (NB + 255) >> 8;
    int b0 = tid * chunkb;
    int s = 0;
    for (int j = 0; j < chunkb; ++j) {
        int b = b0 + j;
        if (b < NB) s += grow[b];
    }
    int lane = tid & 63, w = tid >> 6;
    int sc = s;
#pragma unroll
    for (int off = 1; off < 64; off <<= 1) {
        int t = __shfl_up(sc, off, 64);
        if (lane >= off) sc += t;
    }
    if (lane == 63) wsum[w] = sc;
    __syncthreads();
    if (tid == 0) { int a = 0; for (int i = 0; i < 4; ++i) { int t = wsum[i]; wsum[i] = a; a += t; } }
    __syncthreads();
    int run = sc - s + wsum[w];
    for (int j = 0; j < chunkb; ++j) {
        int b = b0 + j;
        if (b < NB) {
            lbase[b] = run;
            run += grow[b];
            bbase[b] = cptr[b] + prow[b];
            ccur[b] = 0;
        }
    }
    __syncthreads();

    // LDS scatter (random LDS, cheap)
    for (int i = base + tid; i < end; i += 256) {
        int d = dst[i];
        int b = d >> CSHIFT;
        int off = atomicAdd(&ccur[b], 1);
        int pos = lbase[b] + off;
        bufp[pos] = ((unsigned)(d & (BUCKN - 1)) << 17) | (unsigned)src[i];
        bufb[pos] = (unsigned short)b;
    }
    __syncthreads();

    // flush: consecutive local positions within a bucket -> consecutive global
    for (int i = tid; i < cnt; i += 256) {
        int b = bufb[i];
        stage[bbase[b] + (i - lbase[b])] = bufp[i];
    }
}

// pass 2: per-bucket fine counting-sort (128-node buckets) with LDS-staged coalesced output.
__global__ __launch_bounds__(512) void p2(const unsigned* __restrict__ stage,
    const int* __restrict__ cptr, int* __restrict__ colsrc, int* __restrict__ row_ptr, int n)
{
    int b = blockIdx.x;
    int nbase = b << CSHIFT;
    int NN = n - nbase; if (NN > BUCKN) NN = BUCKN;
    __shared__ int h[BUCKN], bps[BUCKN], cc[BUCKN];
    __shared__ int wsum[2];
    __shared__ int buf[FBUF];   // 36KB staged colsrc image
    int tid = threadIdx.x;
    if (tid < BUCKN) { h[tid] = 0; cc[tid] = 0; }
    __syncthreads();
    int s0 = cptr[b], s1 = cptr[b + 1];
    int span = s1 - s0;
    for (int i = s0 + tid; i < s1; i += 512)
        atomicAdd(&h[stage[i] >> 17], 1);
    __syncthreads();
    // scan 128 bins (first 2 waves)
    if (tid < BUCKN) {
        int v = h[tid];
        int lane = tid & 63, w = tid >> 6;
        int sc = v;
#pragma unroll
        for (int off = 1; off < 64; off <<= 1) {
            int t = __shfl_up(sc, off, 64);
            if (lane >= off) sc += t;
        }
        if (lane == 63) wsum[w] = sc;
        __syncthreads();
        if (tid == 0) { int a = 0; for (int i = 0; i < 2; ++i) { int t = wsum[i]; wsum[i] = a; a += t; } }
        __syncthreads();
        int excl = sc - v + wsum[w];
        bps[tid] = excl;                       // bucket-LOCAL offset
        if (tid < NN) row_ptr[nbase + tid] = s0 + excl;
    } else {
        __syncthreads();
        __syncthreads();
    }
    __syncthreads();

    if (span <= FBUF) {
        // staged: scatter into LDS, flush coalesced
        for (int i = s0 + tid; i < s1; i += 512) {
            unsigned p = stage[i];
            int f = p >> 17;
            int off = atomicAdd(&cc[f], 1);
            buf[bps[f] + off] = (int)(p & 0x1FFFFu);
        }
        __syncthreads();
        for (int i = tid; i < span; i += 512)
            colsrc[s0 + i] = buf[i];
    } else {
        // fallback for pathological bucket: direct scatter
        for (int i = s0 + tid; i < s1; i += 512) {
            unsigned p = stage[i];
            int f = p >> 17;
            int off = atomicAdd(&cc[f], 1);
            colsrc[s0 + bps[f] + off] = (int)(p & 0x1FFFFu);
        }
    }
}

// ============================ gathers (packed 32B rows, 16 lanes/node, 4 nodes/wave) ============================

// Layer 1 gather -> h' packed (16B fp16 h' | fp32 as2 | pad); ad2 separate.
// as2/ad2 via precomputed W2@a2s / W2@a2d (aggregation commutes with W2).
__global__ __launch_bounds__(256) void k_gather8f(const int* __restrict__ row_ptr,
    const int* __restrict__ colsrc, const float4* __restrict__ featpk, const float* __restrict__ ad,
    const float* __restrict__ b1, const float* __restrict__ W2,
    const float* __restrict__ a2s, const float* __restrict__ a2d,
    float4* __restrict__ outpk, float* __restrict__ ad2, int n)
{
    __shared__ float w2as[8], w2ad[8], b1v[8];
    if (threadIdx.x < 8) {
        float s = 0.f, d = 0.f;
#pragma unroll
        for (int c = 0; c < 16; ++c) {
            float wv = W2[threadIdx.x * 16 + c];
            s += wv * a2s[c];
            d += wv * a2d[c];
        }
        w2as[threadIdx.x] = s;
        w2ad[threadIdx.x] = d;
        b1v[threadIdx.x] = b1[threadIdx.x];
    }
    __syncthreads();

    int wid  = (blockIdx.x * 256 + threadIdx.x) >> 6;
    int lane = threadIdx.x & 63;
    int l16  = lane & 15;
    int node = wid * 4 + (lane >> 4);
    bool active = node < n;

    int start = 0, end = 0;
    float adn = 0.f;
    if (active) { start = row_ptr[node]; end = row_ptr[node + 1]; adn = ad[node]; }

    float wsum = 0.f, acc[8];
#pragma unroll
    for (int k = 0; k < 8; ++k) acc[k] = 0.f;

    for (int i = start + l16; i < end; i += 16) {
        int s = colsrc[i];
        union { float4 fv; __half2 h[4]; } u;
        u.fv = featpk[2 * (size_t)s];            // 16B fp16 h row
        float4 meta = featpk[2 * (size_t)s + 1]; // alpha_s in .x (same 32B line)
        float t = meta.x + adn;
        float w = __expf(t > 0.f ? t : NEG * t); // max-shift skipped: |t| small, exact ratio
        wsum += w;
#pragma unroll
        for (int q = 0; q < 4; ++q) {
            float2 hv = __half22float2(u.h[q]);
            acc[2 * q + 0] += w * hv.x;
            acc[2 * q + 1] += w * hv.y;
        }
    }
#pragma unroll
    for (int off = 8; off; off >>= 1) {
        wsum += __shfl_xor(wsum, off, 64);
#pragma unroll
        for (int k = 0; k < 8; ++k) acc[k] += __shfl_xor(acc[k], off, 64);
    }
    if (!active || l16 != 0) return;

    float inv = wsum > 0.f ? 1.f / wsum : 0.f;
    float h[8], s2 = 0.f, d2 = 0.f;
    union { float4 f; __half2 hh[4]; } u;
#pragma unroll
    for (int k = 0; k < 8; ++k) {
        float v = acc[k] * inv + b1v[k];
        h[k] = v > 0.f ? v : 0.f;
        s2 += h[k] * w2as[k];
        d2 += h[k] * w2ad[k];
    }
#pragma unroll
    for (int q = 0; q < 4; ++q) u.hh[q] = __floats2half2_rn(h[2 * q], h[2 * q + 1]);
    outpk[2 * (size_t)node]     = u.f;
    outpk[2 * (size_t)node + 1] = make_float4(s2, 0.f, 0.f, 0.f);
    ad2[node] = d2;
}

// Layer 2 gather on packed h' (8-dim), W2 per-node after normalization, fused log_softmax.
__global__ __launch_bounds__(256) void k_gather16(const int* __restrict__ row_ptr,
    const int* __restrict__ colsrc, const float4* __restrict__ featpk, const float* __restrict__ ad,
    const float* __restrict__ W2, const float* __restrict__ bias, float* __restrict__ outp, int n)
{
    __shared__ float w2s[128], bv[16];
    if (threadIdx.x < 128) w2s[threadIdx.x] = W2[threadIdx.x];
    else if (threadIdx.x < 144) bv[threadIdx.x - 128] = bias[threadIdx.x - 128];
    __syncthreads();

    int wid  = (blockIdx.x * 256 + threadIdx.x) >> 6;
    int lane = threadIdx.x & 63;
    int l16  = lane & 15;
    int node = wid * 4 + (lane >> 4);
    bool active = node < n;

    int start = 0, end = 0;
    float adn = 0.f;
    if (active) { start = row_ptr[node]; end = row_ptr[node + 1]; adn = ad[node]; }

    float wsum = 0.f, acc[8];
#pragma unroll
    for (int k = 0; k < 8; ++k) acc[k] = 0.f;

    for (int i = start + l16; i < end; i += 16) {
        int s = colsrc[i];
        union { float4 fv; __half2 h[4]; } u;
        u.fv = featpk[2 * (size_t)s];
        float4 meta = featpk[2 * (size_t)s + 1];
        float t = meta.x + adn;
        float w = __expf(t > 0.f ? t : NEG * t);
        wsum += w;
#pragma unroll
        for (int q = 0; q < 4; ++q) {
            float2 hv = __half22float2(u.h[q]);
            acc[2 * q + 0] += w * hv.x;
            acc[2 * q + 1] += w * hv.y;
        }
    }
#pragma unroll
    for (int off = 8; off; off >>= 1) {
        wsum += __shfl_xor(wsum, off, 64);
#pragma unroll
        for (int k = 0; k < 8; ++k) acc[k] += __shfl_xor(acc[k], off, 64);
    }
    if (!active) return;

    float inv = wsum > 0.f ? 1.f / wsum : 0.f;
    float o = bv[l16];
#pragma unroll
    for (int k = 0; k < 8; ++k) o += (acc[k] * inv) * w2s[k * 16 + l16];
    float m = o;
#pragma unroll
    for (int off = 8; off; off >>= 1) m = fmaxf(m, __shfl_xor(m, off, 64));
    float se = __expf(o - m);
#pragma unroll
    for (int off = 8; off; off >>= 1) se += __shfl_xor(se, off, 64);
    float l = m + __logf(se);
    outp[(size_t)node * 16 + l16] = o - l;
}

// ============================ fallback: pure atomic path (fp32) ============================

__global__ __launch_bounds__(256) void k1_nodeF(const float* __restrict__ x,
    const float* __restrict__ W1, const float* __restrict__ a1s, const float* __restrict__ a1d,
    float* __restrict__ h1, float* __restrict__ as1, float* __restrict__ ad1, int n)
{
    __shared__ float wt[8 * 128];
    __shared__ float av[16];
    for (int i = threadIdx.x; i < 1024; i += 256) {
        int r = i >> 3, k = i & 7;
        wt[k * 128 + r] = W1[i];
    }
    if (threadIdx.x < 8)        av[threadIdx.x] = a1s[threadIdx.x];
    else if (threadIdx.x < 16)  av[threadIdx.x] = a1d[threadIdx.x - 8];
    __syncthreads();

    int lane = threadIdx.x & 31;
    int node = blockIdx.x * 8 + (threadIdx.x >> 5);
    if (node >= n) return;

    float4 xv = ((const float4*)(x + (size_t)node * 128))[lane];
    float p[8];
#pragma unroll
    for (int k = 0; k < 8; ++k) {
        float4 wv = ((const float4*)(wt + k * 128))[lane];
        p[k] = xv.x * wv.x + xv.y * wv.y + xv.z * wv.z + xv.w * wv.w;
    }
#pragma unroll
    for (int off = 16; off; off >>= 1)
#pragma unroll
        for (int k = 0; k < 8; ++k) p[k] += __shfl_down(p[k], off, 32);

    if (lane == 0) {
        float s = 0.f, d = 0.f;
#pragma unroll
        for (int k = 0; k < 8; ++k) {
            h1[(size_t)node * 8 + k] = p[k];
            s += p[k] * av[k];
            d += p[k] * av[8 + k];
        }
        as1[node] = s;
        ad1[node] = d;
    }
}

template <int F>
__global__ __launch_bounds__(256) void k_edge(const int* __restrict__ src, const int* __restrict__ dst,
    const float* __restrict__ as, const float* __restrict__ ad, const float* __restrict__ feat,
    float* __restrict__ denom, float* __restrict__ acc, int E)
{
    int e = blockIdx.x * 256 + threadIdx.x;
    if (e >= E) return;
    int s = src[e], d = dst[e];
    float t = as[s] + ad[d];
    float w = __expf(t > 0.f ? t : NEG * t);
    atomicAdd(denom + d, w);
    const float* fs = feat + (size_t)s * F;
    float* ac = acc + (size_t)d * F;
#pragma unroll
    for (int k = 0; k < F; ++k) atomicAdd(ac + k, w * fs[k]);
}

__global__ __launch_bounds__(256) void k3_node(const float* __restrict__ denom1,
    const float* __restrict__ acc1, const float* __restrict__ b1,
    const float* __restrict__ W2, const float* __restrict__ a2s, const float* __restrict__ a2d,
    float* __restrict__ g, float* __restrict__ as2, float* __restrict__ ad2, int n)
{
    __shared__ float w2[128];
    __shared__ float aa[32];
    __shared__ float bb[8];
    if (threadIdx.x < 128) w2[threadIdx.x] = W2[threadIdx.x];
    if (threadIdx.x >= 128 && threadIdx.x < 144) aa[threadIdx.x - 128] = a2s[threadIdx.x - 128];
    if (threadIdx.x >= 144 && threadIdx.x < 160) aa[16 + threadIdx.x - 144] = a2d[threadIdx.x - 144];
    if (threadIdx.x >= 160 && threadIdx.x < 168) bb[threadIdx.x - 160] = b1[threadIdx.x - 160];
    __syncthreads();

    int node = blockIdx.x * 256 + threadIdx.x;
    if (node >= n) return;
    float dn = denom1[node];
    float inv = dn > 0.f ? 1.f / dn : 0.f;
    float h[8];
#pragma unroll
    for (int k = 0; k < 8; ++k) {
        float v = acc1[(size_t)node * 8 + k] * inv + bb[k];
        h[k] = v > 0.f ? v : 0.f;
    }
    float s = 0.f, dd = 0.f;
#pragma unroll
    for (int c = 0; c < 16; ++c) {
        float gv = 0.f;
#pragma unroll
        for (int k = 0; k < 8; ++k) gv += h[k] * w2[k * 16 + c];
        g[(size_t)node * 16 + c] = gv;
        s += gv * aa[c];
        dd += gv * aa[16 + c];
    }
    as2[node] = s;
    ad2[node] = dd;
}

__global__ __launch_bounds__(256) void k5_final(const float* __restrict__ denom2,
    const float* __restrict__ acc2, const float* __restrict__ b2, float* __restrict__ out, int n)
{
    __shared__ float bb[16];
    if (threadIdx.x < 16) bb[threadIdx.x] = b2[threadIdx.x];
    __syncthreads();

    int node = blockIdx.x * 256 + threadIdx.x;
    if (node >= n) return;
    float dn = denom2[node];
    float inv = dn > 0.f ? 1.f / dn : 0.f;
    float o[16];
    float m = -1e30f;
#pragma unroll
    for (int c = 0; c < 16; ++c) {
        o[c] = acc2[(size_t)node * 16 + c] * inv + bb[c];
        m = fmaxf(m, o[c]);
    }
    float se = 0.f;
#pragma unroll
    for (int c = 0; c < 16; ++c) {
        o[c] -= m;
        se += __expf(o[c]);
    }
    float l = __logf(se);
#pragma unroll
    for (int c = 0; c < 16; ++c) out[(size_t)node * 16 + c] = o[c] - l;
}

// ============================ launch ============================

static inline char* align256(char* p) {
    return (char*)(((uintptr_t)p + 255) & ~(uintptr_t)255);
}

extern "C" void kernel_launch(void* const* d_in, const int* in_sizes, int n_in,
                              void* d_out, int out_size, void* d_ws, size_t ws_size,
                              hipStream_t stream)
{
    const float* x    = (const float*)d_in[0];
    const int*   eidx = (const int*)d_in[1];
    const float* W1   = (const float*)d_in[2];
    const float* a1s  = (const float*)d_in[3];
    const float* a1d  = (const float*)d_in[4];
    const float* b1   = (const float*)d_in[5];
    const float* W2   = (const float*)d_in[6];
    const float* a2s  = (const float*)d_in[7];
    const float* a2d  = (const float*)d_in[8];
    const float* b2   = (const float*)d_in[9];
    float* out = (float*)d_out;

    const int n = in_sizes[0] / 128;
    const int E = in_sizes[1] / 2;
    const int* src = eidx;
    const int* dst = eidx + E;
    const int NB = (n + BUCKN - 1) >> CSHIFT;
    const int NBLK = (E + CHUNK - 1) / CHUNK;

    // ---- tier-0: bucket-sort CSR (gmat/pbaseRel aliased into colsrc) + packed fp16 gathers ----
    {
        char* p = (char*)d_ws;
        char* p0 = p;
        unsigned* stage = (unsigned*)p;  p = align256(p + (size_t)E * 4);
        int* colsrc  = (int*)p;          p = align256(p + (size_t)E * 4);
        int* total   = (int*)p;          p = align256(p + (size_t)NB * 4);
        int* cptr    = (int*)p;          p = align256(p + (size_t)(NB + 1) * 4);
        int* row_ptr = (int*)p;          p = align256(p + (size_t)(n + 1) * 4);
        float4* h1pk  = (float4*)p;      p = align256(p + (size_t)n * 32);
        float4* h1ppk = (float4*)p;      p = align256(p + (size_t)n * 32);
        float* ad1   = (float*)p;        p = align256(p + (size_t)n * 4);
        float* ad2   = (float*)p;        p = align256(p + (size_t)n * 4);
        size_t needed = (size_t)(p - p0);

        int* gmat     = colsrc;                       // alias (dead before p2)
        int* pbaseRel = (int*)align256((char*)(colsrc + (size_t)NBLK * NB));

        bool alias_ok = ((size_t)2 * NBLK * NB + 64) <= (size_t)E;

        if (n <= 131072 && NB <= MAXNB && alias_ok && ws_size >= needed) {
            k1_node<<<(n + 7) / 8, 256, 0, stream>>>(x, W1, a1s, a1d, h1pk, ad1, n);

            p1a<<<NBLK, 256, 0, stream>>>(dst, gmat, E, NB);
            pcol<<<NB, 256, 0, stream>>>(gmat, pbaseRel, total, NBLK, NB);
            ptot<<<1, 512, 0, stream>>>(total, cptr, row_ptr, NB, n, E);
            p1bW<<<NBLK, 256, 0, stream>>>(src, dst, gmat, cptr, pbaseRel, stage, E, NB);
            p2<<<NB, 512, 0, stream>>>(stage, cptr, colsrc, row_ptr, n);

            // 16 lanes per node, 4 nodes per wave
            const int gblocks = ((size_t)n * 16 + 255) / 256;
            k_gather8f<<<gblocks, 256, 0, stream>>>(row_ptr, colsrc, h1pk, ad1,
                                                    b1, W2, a2s, a2d, h1ppk, ad2, n);
            k_gather16<<<gblocks, 256, 0, stream>>>(row_ptr, colsrc, h1ppk, ad2, W2, b2, out, n);
            return;
        }
    }

    // ---- fallback: pure atomic path (fp32) ----
    {
        float* ws     = (float*)d_ws;
        float* denom1 = ws;
        float* acc1   = ws + (size_t)n;
        float* denom2 = ws + (size_t)9 * n;
        float* acc2   = ws + (size_t)10 * n;
        float* h1     = ws + (size_t)26 * n;
        float* as1    = ws + (size_t)34 * n;
        float* ad1    = ws + (size_t)35 * n;
        float* g      = ws + (size_t)36 * n;
        float* as2    = ws + (size_t)52 * n;
        float* ad2    = ws + (size_t)53 * n;

        hipMemsetAsync(ws, 0, (size_t)26 * n * sizeof(float), stream);
        k1_nodeF<<<(n + 7) / 8, 256, 0, stream>>>(x, W1, a1s, a1d, h1, as1, ad1, n);
        k_edge<8><<<(E + 255) / 256, 256, 0, stream>>>(src, dst, as1, ad1, h1, denom1, acc1, E);
        k3_node<<<(n + 255) / 256, 256, 0, stream>>>(denom1, acc1, b1, W2, a2s, a2d, g, as2, ad2, n);
        k_edge<16><<<(E + 255) / 256, 256, 0, stream>>>(src, dst, as2, ad2, g, denom2, acc2, E);
        k5_final<<<(n + 255) / 256, 256, 0, stream>>>(denom2, acc2, b2, out, n);
    }
}